// Round 7
// baseline (465.434 us; speedup 1.0000x reference)
//
#include <hip/hip_runtime.h>

#define Nn 50000
#define Ee 800000
#define INF_ 256
#define HID 128
#define NC 40
#define CAPD 48      // adj_dst row capacity (Poisson(16) tail @48 ~1e-11)
#define CAPS 48      // adj_s row capacity (u-list front, m-list back)
#define LPA_ITERS 10
#define NB 98        // node buckets of 512
#define BSH 9
#define EPB 2048     // edges per bin_edges block
#define NBLK ((Ee + EPB - 1) / EPB)   // 391
#define CAPB_D 10240 // per-bucket bin capacity, dst direction (mean 8163)
#define CAPB_S 6144  // per-bucket bin capacity, src/unmasked (mean ~4081)

// ---------------------------------------------------------------------------
__global__ void detect_fmt(const unsigned int* __restrict__ m, int* flag) {
    int i = blockIdx.x * blockDim.x + threadIdx.x;
    if (i < 12500) {
        if (m[i] > 1u) atomicOr(flag, 1);
    }
}

__device__ inline bool read_mask(const void* mask, int node, int fmt) {
    if (fmt) return ((const unsigned char*)mask)[node] != 0;
    return ((const int*)mask)[node] != 0;
}

// ---------------------------------------------------------------------------
// Single-pass edge binning, both directions, one edge read. Fixed-capacity
// global bins (no prepass); LDS staging -> coalesced writebacks.
__global__ __launch_bounds__(256) void bin_edges(
    const int* __restrict__ src, const int* __restrict__ dst,
    const void* __restrict__ mask, const int* __restrict__ flag,
    int* __restrict__ cnt_src,
    int* __restrict__ cur_d, int* __restrict__ cur_s,
    unsigned* __restrict__ bkt_d, unsigned* __restrict__ bkt_s) {
    __shared__ unsigned stage_d[EPB];
    __shared__ unsigned stage_s[EPB];
    __shared__ int hd[NB], od[NB + 1], cd[NB], gd_[NB];
    __shared__ int hs[NB], os_[NB + 1], cs_[NB], gs_[NB];
    int tid = threadIdx.x;
    int e0 = blockIdx.x * EPB;
    int fmt = *flag;
    if (tid < NB) { hd[tid] = 0; hs[tid] = 0; }
    __syncthreads();

    int rs[EPB / 256], rd[EPB / 256];
    unsigned um = 0;  // bit k: src unmasked
#pragma unroll
    for (int k = 0; k < EPB / 256; k++) {
        int e = e0 + tid + k * 256;
        rs[k] = -1; rd[k] = -1;
        if (e < Ee) {
            int s = src[e], d = dst[e];
            rs[k] = s; rd[k] = d;
            atomicAdd(&cnt_src[s], 1);
            atomicAdd(&hd[d >> BSH], 1);
            if (!read_mask(mask, s, fmt)) {
                um |= (1u << k);
                atomicAdd(&hs[s >> BSH], 1);
            }
        }
    }
    __syncthreads();
    if (tid == 0) {
        int run = 0;
        for (int b = 0; b < NB; b++) { od[b] = run; run += hd[b]; }
        od[NB] = run;
        run = 0;
        for (int b = 0; b < NB; b++) { os_[b] = run; run += hs[b]; }
        os_[NB] = run;
    }
    __syncthreads();
    if (tid < NB) {
        gd_[tid] = hd[tid] ? atomicAdd(&cur_d[tid], hd[tid]) : 0;
        gs_[tid] = hs[tid] ? atomicAdd(&cur_s[tid], hs[tid]) : 0;
        cd[tid] = od[tid];
        cs_[tid] = os_[tid];
    }
    __syncthreads();
#pragma unroll
    for (int k = 0; k < EPB / 256; k++) {
        if (rd[k] >= 0) {
            int p = atomicAdd(&cd[rd[k] >> BSH], 1);
            stage_d[p] = ((unsigned)rd[k] << 16) | (unsigned)rs[k];
            if (um & (1u << k)) {
                int q = atomicAdd(&cs_[rs[k] >> BSH], 1);
                stage_s[q] = ((unsigned)rs[k] << 16) | (unsigned)rd[k];
            }
        }
    }
    __syncthreads();
    int totd = od[NB];
    for (int i = tid; i < totd; i += 256) {
        int lo = 0, hi = NB;
        while (hi - lo > 1) {
            int mid = (lo + hi) >> 1;
            if (od[mid] <= i) lo = mid; else hi = mid;
        }
        int pos = gd_[lo] + (i - od[lo]);
        if (pos < CAPB_D) bkt_d[(size_t)lo * CAPB_D + pos] = stage_d[i];
    }
    int tots = os_[NB];
    for (int i = tid; i < tots; i += 256) {
        int lo = 0, hi = NB;
        while (hi - lo > 1) {
            int mid = (lo + hi) >> 1;
            if (os_[mid] <= i) lo = mid; else hi = mid;
        }
        int pos = gs_[lo] + (i - os_[lo]);
        if (pos < CAPB_S) bkt_s[(size_t)lo * CAPB_S + pos] = stage_s[i];
    }
}

// Phase B (dst)
__global__ __launch_bounds__(256) void build_csr_dst(
    const unsigned* __restrict__ bkt, const int* __restrict__ cur,
    int* __restrict__ adj, int* __restrict__ cnt) {
    __shared__ int lc[512];
    int b = blockIdx.x, tid = threadIdx.x;
    lc[tid] = 0; lc[tid + 256] = 0;
    __syncthreads();
    int n = cur[b]; if (n > CAPB_D) n = CAPB_D;
    int n0 = b << BSH;
    const unsigned* base = bkt + (size_t)b * CAPB_D;
    for (int i = tid; i < n; i += 256) {
        unsigned r = base[i];
        int d = r >> 16, s = r & 0xffff;
        int sl = atomicAdd(&lc[d - n0], 1);
        if (sl < CAPD) adj[d * CAPD + sl] = s;
    }
    __syncthreads();
    int g0 = n0 + tid;
    if (g0 < Nn) cnt[g0] = lc[tid];
    g0 += 256;
    if (g0 < Nn) cnt[g0] = lc[tid + 256];
}

// Phase B (src): unmasked dst -> row front, masked dst -> row back.
__global__ __launch_bounds__(256) void build_csr_src(
    const unsigned* __restrict__ bkt, const int* __restrict__ cur,
    const void* __restrict__ mask, const int* __restrict__ flag,
    int* __restrict__ adj, int* __restrict__ cnt_u, int* __restrict__ cnt_m) {
    __shared__ int lu[512], lm[512];
    int b = blockIdx.x, tid = threadIdx.x;
    lu[tid] = 0; lu[tid + 256] = 0; lm[tid] = 0; lm[tid + 256] = 0;
    __syncthreads();
    int fmt = *flag;
    int n = cur[b]; if (n > CAPB_S) n = CAPB_S;
    int n0 = b << BSH;
    const unsigned* base = bkt + (size_t)b * CAPB_S;
    for (int i = tid; i < n; i += 256) {
        unsigned r = base[i];
        int s = r >> 16, d = r & 0xffff;
        if (read_mask(mask, d, fmt)) {
            int sl = atomicAdd(&lm[s - n0], 1);
            if (sl < CAPS) adj[s * CAPS + (CAPS - 1 - sl)] = d;
        } else {
            int sl = atomicAdd(&lu[s - n0], 1);
            if (sl < CAPS) adj[s * CAPS + sl] = d;
        }
    }
    __syncthreads();
    int g0 = n0 + tid;
    if (g0 < Nn) { cnt_u[g0] = lu[tid]; cnt_m[g0] = lm[tid]; }
    g0 += 256;
    if (g0 < Nn) { cnt_u[g0] = lu[tid + 256]; cnt_m[g0] = lm[tid + 256]; }
}

__global__ void build_unmasked(const void* __restrict__ mask,
                               const int* __restrict__ flag,
                               int* n_un, int* __restrict__ ulist) {
    int i = blockIdx.x * blockDim.x + threadIdx.x;
    if (i < Nn) {
        if (!read_mask(mask, i, *flag)) {
            int p = atomicAdd(n_un, 1);
            ulist[p] = i;
        }
    }
}

// ---------------------------------------------------------------------------
// GEMM1 v3: h1[n, j] = (sum_k feat[n,k] * W1[k,j]) * norm_src[n]
// 128x128 block tile, 8x8 thread tile. A staged as float4 k-chunks with XOR
// swizzle (chunk ^ ((row>>3)&7)) so the wave's 4 distinct A-addresses hit 4
// distinct bank-quads (conflict-free). Per 4 k: 16 b128 vs 512 FMA-cycles.
#define G1_TILE 128
#define G1_KT 32
__global__ __launch_bounds__(256) void gemm1(
    const float* __restrict__ feat, const float* __restrict__ W1,
    const int* __restrict__ cnt_src, float* __restrict__ h1) {
    __shared__ float4 lA4[G1_TILE][8];   // [row][kchunk], swizzled; 16KB
    __shared__ float lB[G1_KT][HID];     // [k][col]; 16KB
    const int tid = threadIdx.x;
    const int row0 = blockIdx.x * G1_TILE;
    const int r0 = (tid >> 4) * 8;   // 16 row-groups of 8
    const int c0 = (tid & 15) * 8;   // 16 col-groups of 8
    const int key = (tid >> 4) & 7;  // swizzle key = (r0>>3)&7

    float4 acc[8][2];
#pragma unroll
    for (int i = 0; i < 8; i++) {
        acc[i][0] = make_float4(0.f, 0.f, 0.f, 0.f);
        acc[i][1] = make_float4(0.f, 0.f, 0.f, 0.f);
    }

    for (int k0 = 0; k0 < INF_; k0 += G1_KT) {
        // stage A: 128 rows x 8 chunks = 1024 float4, 4/thread, swizzled
#pragma unroll
        for (int p = 0; p < 4; p++) {
            int idx = tid + p * 256;
            int r = idx >> 3, c = idx & 7;
            int grow = row0 + r;
            float4 v = make_float4(0.f, 0.f, 0.f, 0.f);
            if (grow < Nn)
                v = *(const float4*)(feat + (size_t)grow * INF_ + k0 + c * 4);
            lA4[r][c ^ ((r >> 3) & 7)] = v;
        }
        // stage B: 32 k x 128 cols = 1024 float4, 4/thread
#pragma unroll
        for (int p = 0; p < 4; p++) {
            int idx = tid + p * 256;
            int kb = idx >> 5, c4 = idx & 31;
            *(float4*)(&lB[kb][c4 * 4]) =
                *(const float4*)(W1 + (size_t)(k0 + kb) * HID + c4 * 4);
        }
        __syncthreads();
#pragma unroll
        for (int k4 = 0; k4 < 8; k4++) {
            float4 av[8];
#pragma unroll
            for (int i = 0; i < 8; i++) av[i] = lA4[r0 + i][k4 ^ key];
#pragma unroll
            for (int kk = 0; kk < 4; kk++) {
                const float* bk = &lB[k4 * 4 + kk][c0];
                float4 b0 = *(const float4*)bk;
                float4 b1 = *(const float4*)(bk + 4);
#pragma unroll
                for (int i = 0; i < 8; i++) {
                    float a = kk == 0 ? av[i].x
                            : kk == 1 ? av[i].y
                            : kk == 2 ? av[i].z : av[i].w;
                    acc[i][0].x += a * b0.x; acc[i][0].y += a * b0.y;
                    acc[i][0].z += a * b0.z; acc[i][0].w += a * b0.w;
                    acc[i][1].x += a * b1.x; acc[i][1].y += a * b1.y;
                    acc[i][1].z += a * b1.z; acc[i][1].w += a * b1.w;
                }
            }
        }
        __syncthreads();
    }
#pragma unroll
    for (int i = 0; i < 8; i++) {
        int grow = row0 + r0 + i;
        if (grow < Nn) {
            int dg = cnt_src[grow];
            float nrm = rsqrtf((float)(dg > 1 ? dg : 1));
            float* op = h1 + (size_t)grow * HID + c0;
            float4 v0, v1;
            v0.x = acc[i][0].x * nrm; v0.y = acc[i][0].y * nrm;
            v0.z = acc[i][0].z * nrm; v0.w = acc[i][0].w * nrm;
            v1.x = acc[i][1].x * nrm; v1.y = acc[i][1].y * nrm;
            v1.z = acc[i][1].z * nrm; v1.w = acc[i][1].w * nrm;
            *(float4*)op = v0;
            *(float4*)(op + 4) = v1;
        }
    }
}

// ---------------------------------------------------------------------------
// agg1: x1[i,:] = relu( norm_dst[i] * sum_{e: dst=i} h1[src_e,:] + b1 )
__global__ __launch_bounds__(256) void agg_relu1(
    const float4* __restrict__ h1, const int* __restrict__ adj_dst,
    const int* __restrict__ cnt_dst, const float4* __restrict__ b1,
    float4* __restrict__ x1) {
    int node = blockIdx.x * 8 + (threadIdx.x >> 5);
    int l = threadIdx.x & 31;
    int dg = cnt_dst[node];
    int cnt = dg < CAPD ? dg : CAPD;
    const int* lst = adj_dst + (size_t)node * CAPD;
    float4 s = make_float4(0.f, 0.f, 0.f, 0.f);
    int e = 0;
    for (; e + 8 <= cnt; e += 8) {
        float4 v[8];
#pragma unroll
        for (int q = 0; q < 8; q++) v[q] = h1[(size_t)lst[e + q] * 32 + l];
#pragma unroll
        for (int q = 0; q < 8; q++) {
            s.x += v[q].x; s.y += v[q].y; s.z += v[q].z; s.w += v[q].w;
        }
    }
    for (; e < cnt; e++) {
        float4 a = h1[(size_t)lst[e] * 32 + l];
        s.x += a.x; s.y += a.y; s.z += a.z; s.w += a.w;
    }
    float nrm = rsqrtf((float)(dg > 1 ? dg : 1));
    float4 bb = b1[l];
    float4 v;
    v.x = fmaxf(s.x * nrm + bb.x, 0.f);
    v.y = fmaxf(s.y * nrm + bb.y, 0.f);
    v.z = fmaxf(s.z * nrm + bb.z, 0.f);
    v.w = fmaxf(s.w * nrm + bb.w, 0.f);
    x1[(size_t)node * 32 + l] = v;
}

// ---------------------------------------------------------------------------
// GEMM2: W2 (20KB) fully in LDS; one thread = one row, broadcast reads.
__global__ __launch_bounds__(256) void gemm2(
    const float4* __restrict__ x1, const float4* __restrict__ W2,
    const int* __restrict__ cnt_src, float* __restrict__ h2) {
    __shared__ float lw[HID * NC];   // 5120 floats = 20KB
    int tid = threadIdx.x;
    for (int i = tid; i < HID * NC / 4; i += 256)
        ((float4*)lw)[i] = W2[i];
    __syncthreads();
    int r = blockIdx.x * 256 + tid;
    if (r >= Nn) return;
    const float4* xr = x1 + (size_t)r * 32;
    float4 acc[10];
#pragma unroll
    for (int j = 0; j < 10; j++) acc[j] = make_float4(0.f, 0.f, 0.f, 0.f);
    for (int k4 = 0; k4 < 32; k4++) {
        float4 xv = xr[k4];
#pragma unroll
        for (int s = 0; s < 4; s++) {
            float x = s == 0 ? xv.x : (s == 1 ? xv.y : (s == 2 ? xv.z : xv.w));
            const float4* wrow = (const float4*)(lw + (k4 * 4 + s) * NC);
#pragma unroll
            for (int j = 0; j < 10; j++) {
                float4 w = wrow[j];
                acc[j].x += x * w.x; acc[j].y += x * w.y;
                acc[j].z += x * w.z; acc[j].w += x * w.w;
            }
        }
    }
    int dg = cnt_src[r];
    float nrm = rsqrtf((float)(dg > 1 ? dg : 1));
    float4* out = (float4*)(h2 + (size_t)r * NC);
#pragma unroll
    for (int j = 0; j < 10; j++) {
        float4 v;
        v.x = acc[j].x * nrm; v.y = acc[j].y * nrm;
        v.z = acc[j].z * nrm; v.w = acc[j].w * nrm;
        out[j] = v;
    }
}

// ---------------------------------------------------------------------------
// agg2: out_x[i,c] = norm_dst[i] * sum_{e: dst=i} h2[src_e,c] + b2[c]
__global__ __launch_bounds__(320) void agg2(
    const float4* __restrict__ h2, const int* __restrict__ adj_dst,
    const int* __restrict__ cnt_dst, const float4* __restrict__ b2,
    float4* __restrict__ out_x) {
    int node = blockIdx.x * 32 + threadIdx.x / 10;
    int l = threadIdx.x % 10;
    if (node >= Nn) return;
    int dg = cnt_dst[node];
    int cnt = dg < CAPD ? dg : CAPD;
    const int* lst = adj_dst + (size_t)node * CAPD;
    float4 s = make_float4(0.f, 0.f, 0.f, 0.f);
    int e = 0;
    for (; e + 8 <= cnt; e += 8) {
        float4 v[8];
#pragma unroll
        for (int q = 0; q < 8; q++) v[q] = h2[(size_t)lst[e + q] * 10 + l];
#pragma unroll
        for (int q = 0; q < 8; q++) {
            s.x += v[q].x; s.y += v[q].y; s.z += v[q].z; s.w += v[q].w;
        }
    }
    for (; e + 4 <= cnt; e += 4) {
        float4 v[4];
#pragma unroll
        for (int q = 0; q < 4; q++) v[q] = h2[(size_t)lst[e + q] * 10 + l];
#pragma unroll
        for (int q = 0; q < 4; q++) {
            s.x += v[q].x; s.y += v[q].y; s.z += v[q].z; s.w += v[q].w;
        }
    }
    for (; e < cnt; e++) {
        float4 a = h2[(size_t)lst[e] * 10 + l];
        s.x += a.x; s.y += a.y; s.z += a.z; s.w += a.w;
    }
    float nrm = rsqrtf((float)(dg > 1 ? dg : 1));
    float4 bb = b2[l];
    float4 v;
    v.x = s.x * nrm + bb.x;
    v.y = s.y * nrm + bb.y;
    v.z = s.z * nrm + bb.z;
    v.w = s.w * nrm + bb.w;
    out_x[(size_t)node * 10 + l] = v;
}

// ---------------------------------------------------------------------------
// LPA
__global__ void lpa_init(const float* __restrict__ labels, const void* mask,
                         const int* __restrict__ flag, float* __restrict__ out_y) {
    int g = blockIdx.x * blockDim.x + threadIdx.x;
    if (g >= Nn * NC) return;
    int node = g / NC;
    if (read_mask(mask, node, *flag)) out_y[g] = labels[g];
}

__global__ __launch_bounds__(320) void lpa_const(
    const float4* __restrict__ labels, const int* __restrict__ n_un,
    const int* __restrict__ ulist, const int* __restrict__ adj_s,
    const int* __restrict__ cnt_m, float4* __restrict__ sconst) {
    int g = blockIdx.x * 32 + threadIdx.x / 10;
    int l = threadIdx.x % 10;
    if (g >= *n_un) return;
    int u = ulist[g];
    int cm = cnt_m[u];
    int cnt = cm < CAPS ? cm : CAPS;
    const int* lst = adj_s + (size_t)u * CAPS + (CAPS - cnt);
    float4 s = make_float4(0.f, 0.f, 0.f, 0.f);
    int e = 0;
    for (; e + 8 <= cnt; e += 8) {
        float4 v[8];
#pragma unroll
        for (int q = 0; q < 8; q++) v[q] = labels[(size_t)lst[e + q] * 10 + l];
#pragma unroll
        for (int q = 0; q < 8; q++) {
            s.x += v[q].x; s.y += v[q].y; s.z += v[q].z; s.w += v[q].w;
        }
    }
    for (; e + 4 <= cnt; e += 4) {
        float4 v[4];
#pragma unroll
        for (int q = 0; q < 4; q++) v[q] = labels[(size_t)lst[e + q] * 10 + l];
#pragma unroll
        for (int q = 0; q < 4; q++) {
            s.x += v[q].x; s.y += v[q].y; s.z += v[q].z; s.w += v[q].w;
        }
    }
    for (; e < cnt; e++) {
        float4 a = labels[(size_t)lst[e] * 10 + l];
        s.x += a.x; s.y += a.y; s.z += a.z; s.w += a.w;
    }
    sconst[(size_t)u * 10 + l] = s;
}

__global__ __launch_bounds__(320) void lpa_step(
    const float4* __restrict__ ycur, const int* __restrict__ n_un,
    const int* __restrict__ ulist, const int* __restrict__ adj_s,
    const int* __restrict__ cnt_u, const float4* __restrict__ sconst,
    float4* __restrict__ ynext) {
    int g = blockIdx.x * 32 + threadIdx.x / 10;
    int l = threadIdx.x % 10;
    if (g >= *n_un) return;
    int u = ulist[g];
    int cu = cnt_u[u];
    int cnt = cu < CAPS ? cu : CAPS;
    const int* lst = adj_s + (size_t)u * CAPS;
    float4 s = sconst[(size_t)u * 10 + l];
    int e = 0;
    for (; e + 8 <= cnt; e += 8) {
        float4 v[8];
#pragma unroll
        for (int q = 0; q < 8; q++) v[q] = ycur[(size_t)lst[e + q] * 10 + l];
#pragma unroll
        for (int q = 0; q < 8; q++) {
            s.x += v[q].x; s.y += v[q].y; s.z += v[q].z; s.w += v[q].w;
        }
    }
    for (; e + 4 <= cnt; e += 4) {
        float4 v[4];
#pragma unroll
        for (int q = 0; q < 4; q++) v[q] = ycur[(size_t)lst[e + q] * 10 + l];
#pragma unroll
        for (int q = 0; q < 4; q++) {
            s.x += v[q].x; s.y += v[q].y; s.z += v[q].z; s.w += v[q].w;
        }
    }
    for (; e < cnt; e++) {
        float4 a = ycur[(size_t)lst[e] * 10 + l];
        s.x += a.x; s.y += a.y; s.z += a.z; s.w += a.w;
    }
    ynext[(size_t)u * 10 + l] = s;
}

// ---------------------------------------------------------------------------
extern "C" void kernel_launch(void* const* d_in, const int* in_sizes, int n_in,
                              void* d_out, int out_size, void* d_ws, size_t ws_size,
                              hipStream_t stream) {
    const float* feat   = (const float*)d_in[0];
    const float* labels = (const float*)d_in[1];
    const void*  mask   = d_in[2];
    const int*   src    = (const int*)d_in[3];
    const int*   dst    = (const int*)d_in[4];
    const float* W1     = (const float*)d_in[5];
    const float* b1     = (const float*)d_in[6];
    const float* W2     = (const float*)d_in[7];
    const float* b2     = (const float*)d_in[8];

    float* out_x = (float*)d_out;
    float* out_y = out_x + (size_t)Nn * NC;

    char* ws = (char*)d_ws;
    size_t off = 0;
    auto alloc = [&](size_t bytes) -> void* {
        void* p = ws + off;
        off += (bytes + 255) & ~(size_t)255;
        return p;
    };
    // --- zeroed header ---
    int* flag    = (int*)alloc(256);   // flag[0]=fmt, flag[1]=n_un
    int* n_un    = flag + 1;
    int* cnt_src = (int*)alloc((size_t)Nn * 4);
    int* cur_d   = (int*)alloc(512);
    int* cur_s   = (int*)alloc(512);
    size_t zero_bytes = off;
    // --- non-zeroed ---
    int* cnt_dst = (int*)alloc((size_t)Nn * 4);
    int* cnt_u   = (int*)alloc((size_t)Nn * 4);
    int* cnt_m   = (int*)alloc((size_t)Nn * 4);
    int* ulist   = (int*)alloc((size_t)Nn * 4);
    // --- big buffers; bucket bins alias h1 (dead before gemm1 writes) ---
    char* uni = (char*)alloc((size_t)Nn * HID * 4);        // 25.6MB union
    unsigned* bkt_d = (unsigned*)uni;                       // ~4.0MB
    unsigned* bkt_s = (unsigned*)(uni + (size_t)NB * CAPB_D * 4); // ~2.4MB
    float* h1 = (float*)uni;
    float* x1 = (float*)alloc((size_t)Nn * HID * 4);
    int* adj_s   = (int*)alloc((size_t)Nn * CAPS * 4);
    int* adj_dst = (int*)alloc((size_t)Nn * CAPD * 4);
    float* h2     = (float*)alloc((size_t)Nn * NC * 4);
    float* sconst = (float*)alloc((size_t)Nn * NC * 4);
    float* yA     = (float*)alloc((size_t)Nn * NC * 4);

    hipMemsetAsync(d_ws, 0, zero_bytes, stream);

    detect_fmt<<<49, 256, 0, stream>>>((const unsigned int*)mask, flag);
    bin_edges<<<NBLK, 256, 0, stream>>>(src, dst, mask, flag, cnt_src,
                                        cur_d, cur_s, bkt_d, bkt_s);
    build_csr_dst<<<NB, 256, 0, stream>>>(bkt_d, cur_d, adj_dst, cnt_dst);
    build_csr_src<<<NB, 256, 0, stream>>>(bkt_s, cur_s, mask, flag,
                                          adj_s, cnt_u, cnt_m);
    build_unmasked<<<196, 256, 0, stream>>>(mask, flag, n_un, ulist);

    gemm1<<<(Nn + G1_TILE - 1) / G1_TILE, 256, 0, stream>>>(feat, W1, cnt_src, h1);
    agg_relu1<<<Nn / 8, 256, 0, stream>>>((const float4*)h1, adj_dst, cnt_dst,
                                          (const float4*)b1, (float4*)x1);
    gemm2<<<196, 256, 0, stream>>>((const float4*)x1, (const float4*)W2,
                                   cnt_src, h2);
    agg2<<<(Nn + 31) / 32, 320, 0, stream>>>((const float4*)h2, adj_dst, cnt_dst,
                                             (const float4*)b2, (float4*)out_x);

    lpa_init<<<(Nn * NC + 255) / 256, 256, 0, stream>>>(labels, mask, flag, out_y);
    lpa_const<<<(Nn + 31) / 32, 320, 0, stream>>>(
        (const float4*)labels, n_un, ulist, adj_s, cnt_m, (float4*)sconst);
    const float* cur = sconst;
    for (int t = 1; t <= LPA_ITERS - 1; t++) {
        float* nxt = (t & 1) ? out_y : yA;   // t=9 (last) -> out_y
        lpa_step<<<(Nn + 31) / 32, 320, 0, stream>>>(
            (const float4*)cur, n_un, ulist, adj_s, cnt_u,
            (const float4*)sconst, (float4*)nxt);
        cur = nxt;
    }
}

// Round 8
// 452.419 us; speedup vs baseline: 1.0288x; 1.0288x over previous
//
#include <hip/hip_runtime.h>

#define Nn 50000
#define Ee 800000
#define INF_ 256
#define HID 128
#define NC 40
#define CAPD 48      // adj_dst row capacity (Poisson(16) tail @48 ~1e-11)
#define CAPS 48      // adj_s row capacity (u-list front, m-list back)
#define LPA_ITERS 10
#define NB 98        // node buckets of 512
#define BSH 9
#define EPB 2048     // edges per bin_edges block
#define NBLK ((Ee + EPB - 1) / EPB)   // 391
#define CAPB_D 10240 // per-bucket bin capacity, dst direction (mean 8163)
#define CAPB_S 6144  // per-bucket bin capacity, src/unmasked (mean ~4081)

// ---------------------------------------------------------------------------
__global__ void detect_fmt(const unsigned int* __restrict__ m, int* flag) {
    int i = blockIdx.x * blockDim.x + threadIdx.x;
    if (i < 12500) {
        if (m[i] > 1u) atomicOr(flag, 1);
    }
}

__device__ inline bool read_mask(const void* mask, int node, int fmt) {
    if (fmt) return ((const unsigned char*)mask)[node] != 0;
    return ((const int*)mask)[node] != 0;
}

// ---------------------------------------------------------------------------
// Single-pass edge binning, both directions, one edge read. Fixed-capacity
// global bins (no prepass); LDS staging -> coalesced writebacks.
__global__ __launch_bounds__(256) void bin_edges(
    const int* __restrict__ src, const int* __restrict__ dst,
    const void* __restrict__ mask, const int* __restrict__ flag,
    int* __restrict__ cnt_src,
    int* __restrict__ cur_d, int* __restrict__ cur_s,
    unsigned* __restrict__ bkt_d, unsigned* __restrict__ bkt_s) {
    __shared__ unsigned stage_d[EPB];
    __shared__ unsigned stage_s[EPB];
    __shared__ int hd[NB], od[NB + 1], cd[NB], gd_[NB];
    __shared__ int hs[NB], os_[NB + 1], cs_[NB], gs_[NB];
    int tid = threadIdx.x;
    int e0 = blockIdx.x * EPB;
    int fmt = *flag;
    if (tid < NB) { hd[tid] = 0; hs[tid] = 0; }
    __syncthreads();

    int rs[EPB / 256], rd[EPB / 256];
    unsigned um = 0;  // bit k: src unmasked
#pragma unroll
    for (int k = 0; k < EPB / 256; k++) {
        int e = e0 + tid + k * 256;
        rs[k] = -1; rd[k] = -1;
        if (e < Ee) {
            int s = src[e], d = dst[e];
            rs[k] = s; rd[k] = d;
            atomicAdd(&cnt_src[s], 1);
            atomicAdd(&hd[d >> BSH], 1);
            if (!read_mask(mask, s, fmt)) {
                um |= (1u << k);
                atomicAdd(&hs[s >> BSH], 1);
            }
        }
    }
    __syncthreads();
    if (tid == 0) {
        int run = 0;
        for (int b = 0; b < NB; b++) { od[b] = run; run += hd[b]; }
        od[NB] = run;
        run = 0;
        for (int b = 0; b < NB; b++) { os_[b] = run; run += hs[b]; }
        os_[NB] = run;
    }
    __syncthreads();
    if (tid < NB) {
        gd_[tid] = hd[tid] ? atomicAdd(&cur_d[tid], hd[tid]) : 0;
        gs_[tid] = hs[tid] ? atomicAdd(&cur_s[tid], hs[tid]) : 0;
        cd[tid] = od[tid];
        cs_[tid] = os_[tid];
    }
    __syncthreads();
#pragma unroll
    for (int k = 0; k < EPB / 256; k++) {
        if (rd[k] >= 0) {
            int p = atomicAdd(&cd[rd[k] >> BSH], 1);
            stage_d[p] = ((unsigned)rd[k] << 16) | (unsigned)rs[k];
            if (um & (1u << k)) {
                int q = atomicAdd(&cs_[rs[k] >> BSH], 1);
                stage_s[q] = ((unsigned)rs[k] << 16) | (unsigned)rd[k];
            }
        }
    }
    __syncthreads();
    int totd = od[NB];
    for (int i = tid; i < totd; i += 256) {
        int lo = 0, hi = NB;
        while (hi - lo > 1) {
            int mid = (lo + hi) >> 1;
            if (od[mid] <= i) lo = mid; else hi = mid;
        }
        int pos = gd_[lo] + (i - od[lo]);
        if (pos < CAPB_D) bkt_d[(size_t)lo * CAPB_D + pos] = stage_d[i];
    }
    int tots = os_[NB];
    for (int i = tid; i < tots; i += 256) {
        int lo = 0, hi = NB;
        while (hi - lo > 1) {
            int mid = (lo + hi) >> 1;
            if (os_[mid] <= i) lo = mid; else hi = mid;
        }
        int pos = gs_[lo] + (i - os_[lo]);
        if (pos < CAPB_S) bkt_s[(size_t)lo * CAPB_S + pos] = stage_s[i];
    }
}

// Phase B (dst)
__global__ __launch_bounds__(256) void build_csr_dst(
    const unsigned* __restrict__ bkt, const int* __restrict__ cur,
    int* __restrict__ adj, int* __restrict__ cnt) {
    __shared__ int lc[512];
    int b = blockIdx.x, tid = threadIdx.x;
    lc[tid] = 0; lc[tid + 256] = 0;
    __syncthreads();
    int n = cur[b]; if (n > CAPB_D) n = CAPB_D;
    int n0 = b << BSH;
    const unsigned* base = bkt + (size_t)b * CAPB_D;
    for (int i = tid; i < n; i += 256) {
        unsigned r = base[i];
        int d = r >> 16, s = r & 0xffff;
        int sl = atomicAdd(&lc[d - n0], 1);
        if (sl < CAPD) adj[d * CAPD + sl] = s;
    }
    __syncthreads();
    int g0 = n0 + tid;
    if (g0 < Nn) cnt[g0] = lc[tid];
    g0 += 256;
    if (g0 < Nn) cnt[g0] = lc[tid + 256];
}

// Phase B (src): unmasked dst -> row front, masked dst -> row back.
__global__ __launch_bounds__(256) void build_csr_src(
    const unsigned* __restrict__ bkt, const int* __restrict__ cur,
    const void* __restrict__ mask, const int* __restrict__ flag,
    int* __restrict__ adj, int* __restrict__ cnt_u, int* __restrict__ cnt_m) {
    __shared__ int lu[512], lm[512];
    int b = blockIdx.x, tid = threadIdx.x;
    lu[tid] = 0; lu[tid + 256] = 0; lm[tid] = 0; lm[tid + 256] = 0;
    __syncthreads();
    int fmt = *flag;
    int n = cur[b]; if (n > CAPB_S) n = CAPB_S;
    int n0 = b << BSH;
    const unsigned* base = bkt + (size_t)b * CAPB_S;
    for (int i = tid; i < n; i += 256) {
        unsigned r = base[i];
        int s = r >> 16, d = r & 0xffff;
        if (read_mask(mask, d, fmt)) {
            int sl = atomicAdd(&lm[s - n0], 1);
            if (sl < CAPS) adj[s * CAPS + (CAPS - 1 - sl)] = d;
        } else {
            int sl = atomicAdd(&lu[s - n0], 1);
            if (sl < CAPS) adj[s * CAPS + sl] = d;
        }
    }
    __syncthreads();
    int g0 = n0 + tid;
    if (g0 < Nn) { cnt_u[g0] = lu[tid]; cnt_m[g0] = lm[tid]; }
    g0 += 256;
    if (g0 < Nn) { cnt_u[g0] = lu[tid + 256]; cnt_m[g0] = lm[tid + 256]; }
}

__global__ void build_unmasked(const void* __restrict__ mask,
                               const int* __restrict__ flag,
                               int* n_un, int* __restrict__ ulist) {
    int i = blockIdx.x * blockDim.x + threadIdx.x;
    if (i < Nn) {
        if (!read_mask(mask, i, *flag)) {
            int p = atomicAdd(n_un, 1);
            ulist[p] = i;
        }
    }
}

// ---------------------------------------------------------------------------
// GEMM1 v4: h1[n, j] = (sum_k feat[n,k] * W1[k,j]) * norm_src[n]
// 64x64 block tile -> 1564 blocks (~6/CU, grid-parallelism fix for N=50000).
// 4x4 thread tile. A staged as float4 k-chunks, swizzle chunk^((row>>2)&7):
// the wave's 4 distinct A-addresses hit 4 distinct bank-quads (conflict-free).
// B-read c0=(tid&15)*4: 16 distinct 16B addrs x4 broadcast = 2-way = free.
#define G1_TILE 64
#define G1_KT 32
__global__ __launch_bounds__(256) void gemm1(
    const float* __restrict__ feat, const float* __restrict__ W1,
    const int* __restrict__ cnt_src, float* __restrict__ h1) {
    __shared__ float4 lA4[G1_TILE][8];   // [row][kchunk], swizzled; 8KB
    __shared__ float lB[G1_KT][G1_TILE]; // [k][col]; 8KB
    const int tid = threadIdx.x;
    const int rt = blockIdx.x >> 1;
    const int ct = blockIdx.x & 1;
    const int row0 = rt * G1_TILE;
    const int col0 = ct * G1_TILE;
    const int r0 = (tid >> 4) * 4;   // 16 row-groups of 4
    const int c0 = (tid & 15) * 4;   // 16 col-groups of 4

    float4 acc[4];
#pragma unroll
    for (int i = 0; i < 4; i++) acc[i] = make_float4(0.f, 0.f, 0.f, 0.f);

    for (int k0 = 0; k0 < INF_; k0 += G1_KT) {
        // stage A: 64 rows x 8 chunks = 512 float4, 2/thread, swizzled
#pragma unroll
        for (int p = 0; p < 2; p++) {
            int idx = tid + p * 256;
            int r = idx >> 3, c = idx & 7;
            int grow = row0 + r;
            float4 v = make_float4(0.f, 0.f, 0.f, 0.f);
            if (grow < Nn)
                v = *(const float4*)(feat + (size_t)grow * INF_ + k0 + c * 4);
            lA4[r][c ^ ((r >> 2) & 7)] = v;
        }
        // stage B: 32 k x 64 cols = 512 float4, 2/thread
#pragma unroll
        for (int p = 0; p < 2; p++) {
            int idx = tid + p * 256;
            int kb = idx >> 4, c4 = idx & 15;
            *(float4*)(&lB[kb][c4 * 4]) =
                *(const float4*)(W1 + (size_t)(k0 + kb) * HID + col0 + c4 * 4);
        }
        __syncthreads();
#pragma unroll
        for (int k4 = 0; k4 < 8; k4++) {
            float4 av[4];
#pragma unroll
            for (int i = 0; i < 4; i++) {
                int r = r0 + i;
                av[i] = lA4[r][k4 ^ ((r >> 2) & 7)];
            }
#pragma unroll
            for (int kk = 0; kk < 4; kk++) {
                float4 bv = *(const float4*)(&lB[k4 * 4 + kk][c0]);
#pragma unroll
                for (int i = 0; i < 4; i++) {
                    float a = kk == 0 ? av[i].x
                            : kk == 1 ? av[i].y
                            : kk == 2 ? av[i].z : av[i].w;
                    acc[i].x += a * bv.x; acc[i].y += a * bv.y;
                    acc[i].z += a * bv.z; acc[i].w += a * bv.w;
                }
            }
        }
        __syncthreads();
    }
#pragma unroll
    for (int i = 0; i < 4; i++) {
        int grow = row0 + r0 + i;
        if (grow < Nn) {
            int dg = cnt_src[grow];
            float nrm = rsqrtf((float)(dg > 1 ? dg : 1));
            float4 v;
            v.x = acc[i].x * nrm; v.y = acc[i].y * nrm;
            v.z = acc[i].z * nrm; v.w = acc[i].w * nrm;
            *(float4*)(h1 + (size_t)grow * HID + col0 + c0) = v;
        }
    }
}

// ---------------------------------------------------------------------------
// agg1: x1[i,:] = relu( norm_dst[i] * sum_{e: dst=i} h1[src_e,:] + b1 )
__global__ __launch_bounds__(256) void agg_relu1(
    const float4* __restrict__ h1, const int* __restrict__ adj_dst,
    const int* __restrict__ cnt_dst, const float4* __restrict__ b1,
    float4* __restrict__ x1) {
    int node = blockIdx.x * 8 + (threadIdx.x >> 5);
    int l = threadIdx.x & 31;
    int dg = cnt_dst[node];
    int cnt = dg < CAPD ? dg : CAPD;
    const int* lst = adj_dst + (size_t)node * CAPD;
    float4 s = make_float4(0.f, 0.f, 0.f, 0.f);
    int e = 0;
    for (; e + 8 <= cnt; e += 8) {
        float4 v[8];
#pragma unroll
        for (int q = 0; q < 8; q++) v[q] = h1[(size_t)lst[e + q] * 32 + l];
#pragma unroll
        for (int q = 0; q < 8; q++) {
            s.x += v[q].x; s.y += v[q].y; s.z += v[q].z; s.w += v[q].w;
        }
    }
    for (; e < cnt; e++) {
        float4 a = h1[(size_t)lst[e] * 32 + l];
        s.x += a.x; s.y += a.y; s.z += a.z; s.w += a.w;
    }
    float nrm = rsqrtf((float)(dg > 1 ? dg : 1));
    float4 bb = b1[l];
    float4 v;
    v.x = fmaxf(s.x * nrm + bb.x, 0.f);
    v.y = fmaxf(s.y * nrm + bb.y, 0.f);
    v.z = fmaxf(s.z * nrm + bb.z, 0.f);
    v.w = fmaxf(s.w * nrm + bb.w, 0.f);
    x1[(size_t)node * 32 + l] = v;
}

// ---------------------------------------------------------------------------
// GEMM2: W2 (20KB) fully in LDS; one thread = one row, broadcast reads.
__global__ __launch_bounds__(256) void gemm2(
    const float4* __restrict__ x1, const float4* __restrict__ W2,
    const int* __restrict__ cnt_src, float* __restrict__ h2) {
    __shared__ float lw[HID * NC];   // 5120 floats = 20KB
    int tid = threadIdx.x;
    for (int i = tid; i < HID * NC / 4; i += 256)
        ((float4*)lw)[i] = W2[i];
    __syncthreads();
    int r = blockIdx.x * 256 + tid;
    if (r >= Nn) return;
    const float4* xr = x1 + (size_t)r * 32;
    float4 acc[10];
#pragma unroll
    for (int j = 0; j < 10; j++) acc[j] = make_float4(0.f, 0.f, 0.f, 0.f);
    for (int k4 = 0; k4 < 32; k4++) {
        float4 xv = xr[k4];
#pragma unroll
        for (int s = 0; s < 4; s++) {
            float x = s == 0 ? xv.x : (s == 1 ? xv.y : (s == 2 ? xv.z : xv.w));
            const float4* wrow = (const float4*)(lw + (k4 * 4 + s) * NC);
#pragma unroll
            for (int j = 0; j < 10; j++) {
                float4 w = wrow[j];
                acc[j].x += x * w.x; acc[j].y += x * w.y;
                acc[j].z += x * w.z; acc[j].w += x * w.w;
            }
        }
    }
    int dg = cnt_src[r];
    float nrm = rsqrtf((float)(dg > 1 ? dg : 1));
    float4* out = (float4*)(h2 + (size_t)r * NC);
#pragma unroll
    for (int j = 0; j < 10; j++) {
        float4 v;
        v.x = acc[j].x * nrm; v.y = acc[j].y * nrm;
        v.z = acc[j].z * nrm; v.w = acc[j].w * nrm;
        out[j] = v;
    }
}

// ---------------------------------------------------------------------------
// agg2: out_x[i,c] = norm_dst[i] * sum_{e: dst=i} h2[src_e,c] + b2[c]
__global__ __launch_bounds__(320) void agg2(
    const float4* __restrict__ h2, const int* __restrict__ adj_dst,
    const int* __restrict__ cnt_dst, const float4* __restrict__ b2,
    float4* __restrict__ out_x) {
    int node = blockIdx.x * 32 + threadIdx.x / 10;
    int l = threadIdx.x % 10;
    if (node >= Nn) return;
    int dg = cnt_dst[node];
    int cnt = dg < CAPD ? dg : CAPD;
    const int* lst = adj_dst + (size_t)node * CAPD;
    float4 s = make_float4(0.f, 0.f, 0.f, 0.f);
    int e = 0;
    for (; e + 8 <= cnt; e += 8) {
        float4 v[8];
#pragma unroll
        for (int q = 0; q < 8; q++) v[q] = h2[(size_t)lst[e + q] * 10 + l];
#pragma unroll
        for (int q = 0; q < 8; q++) {
            s.x += v[q].x; s.y += v[q].y; s.z += v[q].z; s.w += v[q].w;
        }
    }
    for (; e + 4 <= cnt; e += 4) {
        float4 v[4];
#pragma unroll
        for (int q = 0; q < 4; q++) v[q] = h2[(size_t)lst[e + q] * 10 + l];
#pragma unroll
        for (int q = 0; q < 4; q++) {
            s.x += v[q].x; s.y += v[q].y; s.z += v[q].z; s.w += v[q].w;
        }
    }
    for (; e < cnt; e++) {
        float4 a = h2[(size_t)lst[e] * 10 + l];
        s.x += a.x; s.y += a.y; s.z += a.z; s.w += a.w;
    }
    float nrm = rsqrtf((float)(dg > 1 ? dg : 1));
    float4 bb = b2[l];
    float4 v;
    v.x = s.x * nrm + bb.x;
    v.y = s.y * nrm + bb.y;
    v.z = s.z * nrm + bb.z;
    v.w = s.w * nrm + bb.w;
    out_x[(size_t)node * 10 + l] = v;
}

// ---------------------------------------------------------------------------
// LPA
__global__ void lpa_init(const float* __restrict__ labels, const void* mask,
                         const int* __restrict__ flag, float* __restrict__ out_y) {
    int g = blockIdx.x * blockDim.x + threadIdx.x;
    if (g >= Nn * NC) return;
    int node = g / NC;
    if (read_mask(mask, node, *flag)) out_y[g] = labels[g];
}

__global__ __launch_bounds__(320) void lpa_const(
    const float4* __restrict__ labels, const int* __restrict__ n_un,
    const int* __restrict__ ulist, const int* __restrict__ adj_s,
    const int* __restrict__ cnt_m, float4* __restrict__ sconst) {
    int g = blockIdx.x * 32 + threadIdx.x / 10;
    int l = threadIdx.x % 10;
    if (g >= *n_un) return;
    int u = ulist[g];
    int cm = cnt_m[u];
    int cnt = cm < CAPS ? cm : CAPS;
    const int* lst = adj_s + (size_t)u * CAPS + (CAPS - cnt);
    float4 s = make_float4(0.f, 0.f, 0.f, 0.f);
    int e = 0;
    for (; e + 8 <= cnt; e += 8) {
        float4 v[8];
#pragma unroll
        for (int q = 0; q < 8; q++) v[q] = labels[(size_t)lst[e + q] * 10 + l];
#pragma unroll
        for (int q = 0; q < 8; q++) {
            s.x += v[q].x; s.y += v[q].y; s.z += v[q].z; s.w += v[q].w;
        }
    }
    for (; e + 4 <= cnt; e += 4) {
        float4 v[4];
#pragma unroll
        for (int q = 0; q < 4; q++) v[q] = labels[(size_t)lst[e + q] * 10 + l];
#pragma unroll
        for (int q = 0; q < 4; q++) {
            s.x += v[q].x; s.y += v[q].y; s.z += v[q].z; s.w += v[q].w;
        }
    }
    for (; e < cnt; e++) {
        float4 a = labels[(size_t)lst[e] * 10 + l];
        s.x += a.x; s.y += a.y; s.z += a.z; s.w += a.w;
    }
    sconst[(size_t)u * 10 + l] = s;
}

__global__ __launch_bounds__(320) void lpa_step(
    const float4* __restrict__ ycur, const int* __restrict__ n_un,
    const int* __restrict__ ulist, const int* __restrict__ adj_s,
    const int* __restrict__ cnt_u, const float4* __restrict__ sconst,
    float4* __restrict__ ynext) {
    int g = blockIdx.x * 32 + threadIdx.x / 10;
    int l = threadIdx.x % 10;
    if (g >= *n_un) return;
    int u = ulist[g];
    int cu = cnt_u[u];
    int cnt = cu < CAPS ? cu : CAPS;
    const int* lst = adj_s + (size_t)u * CAPS;
    float4 s = sconst[(size_t)u * 10 + l];
    int e = 0;
    for (; e + 8 <= cnt; e += 8) {
        float4 v[8];
#pragma unroll
        for (int q = 0; q < 8; q++) v[q] = ycur[(size_t)lst[e + q] * 10 + l];
#pragma unroll
        for (int q = 0; q < 8; q++) {
            s.x += v[q].x; s.y += v[q].y; s.z += v[q].z; s.w += v[q].w;
        }
    }
    for (; e + 4 <= cnt; e += 4) {
        float4 v[4];
#pragma unroll
        for (int q = 0; q < 4; q++) v[q] = ycur[(size_t)lst[e + q] * 10 + l];
#pragma unroll
        for (int q = 0; q < 4; q++) {
            s.x += v[q].x; s.y += v[q].y; s.z += v[q].z; s.w += v[q].w;
        }
    }
    for (; e < cnt; e++) {
        float4 a = ycur[(size_t)lst[e] * 10 + l];
        s.x += a.x; s.y += a.y; s.z += a.z; s.w += a.w;
    }
    ynext[(size_t)u * 10 + l] = s;
}

// ---------------------------------------------------------------------------
extern "C" void kernel_launch(void* const* d_in, const int* in_sizes, int n_in,
                              void* d_out, int out_size, void* d_ws, size_t ws_size,
                              hipStream_t stream) {
    const float* feat   = (const float*)d_in[0];
    const float* labels = (const float*)d_in[1];
    const void*  mask   = d_in[2];
    const int*   src    = (const int*)d_in[3];
    const int*   dst    = (const int*)d_in[4];
    const float* W1     = (const float*)d_in[5];
    const float* b1     = (const float*)d_in[6];
    const float* W2     = (const float*)d_in[7];
    const float* b2     = (const float*)d_in[8];

    float* out_x = (float*)d_out;
    float* out_y = out_x + (size_t)Nn * NC;

    char* ws = (char*)d_ws;
    size_t off = 0;
    auto alloc = [&](size_t bytes) -> void* {
        void* p = ws + off;
        off += (bytes + 255) & ~(size_t)255;
        return p;
    };
    // --- zeroed header ---
    int* flag    = (int*)alloc(256);   // flag[0]=fmt, flag[1]=n_un
    int* n_un    = flag + 1;
    int* cnt_src = (int*)alloc((size_t)Nn * 4);
    int* cur_d   = (int*)alloc(512);
    int* cur_s   = (int*)alloc(512);
    size_t zero_bytes = off;
    // --- non-zeroed ---
    int* cnt_dst = (int*)alloc((size_t)Nn * 4);
    int* cnt_u   = (int*)alloc((size_t)Nn * 4);
    int* cnt_m   = (int*)alloc((size_t)Nn * 4);
    int* ulist   = (int*)alloc((size_t)Nn * 4);
    // --- big buffers; bucket bins alias h1 (dead before gemm1 writes) ---
    char* uni = (char*)alloc((size_t)Nn * HID * 4);        // 25.6MB union
    unsigned* bkt_d = (unsigned*)uni;                       // ~4.0MB
    unsigned* bkt_s = (unsigned*)(uni + (size_t)NB * CAPB_D * 4); // ~2.4MB
    float* h1 = (float*)uni;
    float* x1 = (float*)alloc((size_t)Nn * HID * 4);
    int* adj_s   = (int*)alloc((size_t)Nn * CAPS * 4);
    int* adj_dst = (int*)alloc((size_t)Nn * CAPD * 4);
    float* h2     = (float*)alloc((size_t)Nn * NC * 4);
    float* sconst = (float*)alloc((size_t)Nn * NC * 4);
    float* yA     = (float*)alloc((size_t)Nn * NC * 4);

    hipMemsetAsync(d_ws, 0, zero_bytes, stream);

    detect_fmt<<<49, 256, 0, stream>>>((const unsigned int*)mask, flag);
    bin_edges<<<NBLK, 256, 0, stream>>>(src, dst, mask, flag, cnt_src,
                                        cur_d, cur_s, bkt_d, bkt_s);
    build_csr_dst<<<NB, 256, 0, stream>>>(bkt_d, cur_d, adj_dst, cnt_dst);
    build_csr_src<<<NB, 256, 0, stream>>>(bkt_s, cur_s, mask, flag,
                                          adj_s, cnt_u, cnt_m);
    build_unmasked<<<196, 256, 0, stream>>>(mask, flag, n_un, ulist);

    gemm1<<<((Nn + G1_TILE - 1) / G1_TILE) * 2, 256, 0, stream>>>(
        feat, W1, cnt_src, h1);
    agg_relu1<<<Nn / 8, 256, 0, stream>>>((const float4*)h1, adj_dst, cnt_dst,
                                          (const float4*)b1, (float4*)x1);
    gemm2<<<196, 256, 0, stream>>>((const float4*)x1, (const float4*)W2,
                                   cnt_src, h2);
    agg2<<<(Nn + 31) / 32, 320, 0, stream>>>((const float4*)h2, adj_dst, cnt_dst,
                                             (const float4*)b2, (float4*)out_x);

    lpa_init<<<(Nn * NC + 255) / 256, 256, 0, stream>>>(labels, mask, flag, out_y);
    lpa_const<<<(Nn + 31) / 32, 320, 0, stream>>>(
        (const float4*)labels, n_un, ulist, adj_s, cnt_m, (float4*)sconst);
    const float* cur = sconst;
    for (int t = 1; t <= LPA_ITERS - 1; t++) {
        float* nxt = (t & 1) ? out_y : yA;   // t=9 (last) -> out_y
        lpa_step<<<(Nn + 31) / 32, 320, 0, stream>>>(
            (const float4*)cur, n_un, ulist, adj_s, cnt_u,
            (const float4*)sconst, (float4*)nxt);
        cur = nxt;
    }
}

// Round 9
// 430.950 us; speedup vs baseline: 1.0800x; 1.0498x over previous
//
#include <hip/hip_runtime.h>

#define Nn 50000
#define Ee 800000
#define INF_ 256
#define HID 128
#define NC 40
#define CAPD 48      // adj_dst row capacity (Poisson(16) tail @48 ~1e-11)
#define CAPS 48      // adj_s row capacity (u-list front, m-list back)
#define LPA_ITERS 10
#define NB 98        // node buckets of 512
#define BSH 9
#define EPB 2048     // edges per bin_edges block
#define NBLK ((Ee + EPB - 1) / EPB)   // 391
#define CAPB_D 10240 // per-bucket bin capacity, dst direction (mean 8163)
#define CAPB_S 6144  // per-bucket bin capacity, src/unmasked (mean ~4081)

// ---- bf16 helpers (fp32 math, bf16 storage; RNE rounding) ------------------
__device__ inline unsigned f2bf2(float a, float b) {
    unsigned ua = __float_as_uint(a); ua += 0x7FFFu + ((ua >> 16) & 1u);
    unsigned ub = __float_as_uint(b); ub += 0x7FFFu + ((ub >> 16) & 1u);
    return (ua >> 16) | (ub & 0xFFFF0000u);
}
__device__ inline float bf_lo(unsigned u) { return __uint_as_float(u << 16); }
__device__ inline float bf_hi(unsigned u) { return __uint_as_float(u & 0xFFFF0000u); }

// ---------------------------------------------------------------------------
__global__ void detect_fmt(const unsigned int* __restrict__ m, int* flag) {
    int i = blockIdx.x * blockDim.x + threadIdx.x;
    if (i < 12500) {
        if (m[i] > 1u) atomicOr(flag, 1);
    }
}

__device__ inline bool read_mask(const void* mask, int node, int fmt) {
    if (fmt) return ((const unsigned char*)mask)[node] != 0;
    return ((const int*)mask)[node] != 0;
}

// ---------------------------------------------------------------------------
// Single-pass edge binning, both directions, one edge read. Fixed-capacity
// global bins (no prepass); LDS staging -> coalesced writebacks.
__global__ __launch_bounds__(256) void bin_edges(
    const int* __restrict__ src, const int* __restrict__ dst,
    const void* __restrict__ mask, const int* __restrict__ flag,
    int* __restrict__ cnt_src,
    int* __restrict__ cur_d, int* __restrict__ cur_s,
    unsigned* __restrict__ bkt_d, unsigned* __restrict__ bkt_s) {
    __shared__ unsigned stage_d[EPB];
    __shared__ unsigned stage_s[EPB];
    __shared__ int hd[NB], od[NB + 1], cd[NB], gd_[NB];
    __shared__ int hs[NB], os_[NB + 1], cs_[NB], gs_[NB];
    int tid = threadIdx.x;
    int e0 = blockIdx.x * EPB;
    int fmt = *flag;
    if (tid < NB) { hd[tid] = 0; hs[tid] = 0; }
    __syncthreads();

    int rs[EPB / 256], rd[EPB / 256];
    unsigned um = 0;  // bit k: src unmasked
#pragma unroll
    for (int k = 0; k < EPB / 256; k++) {
        int e = e0 + tid + k * 256;
        rs[k] = -1; rd[k] = -1;
        if (e < Ee) {
            int s = src[e], d = dst[e];
            rs[k] = s; rd[k] = d;
            atomicAdd(&cnt_src[s], 1);
            atomicAdd(&hd[d >> BSH], 1);
            if (!read_mask(mask, s, fmt)) {
                um |= (1u << k);
                atomicAdd(&hs[s >> BSH], 1);
            }
        }
    }
    __syncthreads();
    if (tid == 0) {
        int run = 0;
        for (int b = 0; b < NB; b++) { od[b] = run; run += hd[b]; }
        od[NB] = run;
        run = 0;
        for (int b = 0; b < NB; b++) { os_[b] = run; run += hs[b]; }
        os_[NB] = run;
    }
    __syncthreads();
    if (tid < NB) {
        gd_[tid] = hd[tid] ? atomicAdd(&cur_d[tid], hd[tid]) : 0;
        gs_[tid] = hs[tid] ? atomicAdd(&cur_s[tid], hs[tid]) : 0;
        cd[tid] = od[tid];
        cs_[tid] = os_[tid];
    }
    __syncthreads();
#pragma unroll
    for (int k = 0; k < EPB / 256; k++) {
        if (rd[k] >= 0) {
            int p = atomicAdd(&cd[rd[k] >> BSH], 1);
            stage_d[p] = ((unsigned)rd[k] << 16) | (unsigned)rs[k];
            if (um & (1u << k)) {
                int q = atomicAdd(&cs_[rs[k] >> BSH], 1);
                stage_s[q] = ((unsigned)rs[k] << 16) | (unsigned)rd[k];
            }
        }
    }
    __syncthreads();
    int totd = od[NB];
    for (int i = tid; i < totd; i += 256) {
        int lo = 0, hi = NB;
        while (hi - lo > 1) {
            int mid = (lo + hi) >> 1;
            if (od[mid] <= i) lo = mid; else hi = mid;
        }
        int pos = gd_[lo] + (i - od[lo]);
        if (pos < CAPB_D) bkt_d[(size_t)lo * CAPB_D + pos] = stage_d[i];
    }
    int tots = os_[NB];
    for (int i = tid; i < tots; i += 256) {
        int lo = 0, hi = NB;
        while (hi - lo > 1) {
            int mid = (lo + hi) >> 1;
            if (os_[mid] <= i) lo = mid; else hi = mid;
        }
        int pos = gs_[lo] + (i - os_[lo]);
        if (pos < CAPB_S) bkt_s[(size_t)lo * CAPB_S + pos] = stage_s[i];
    }
}

// Phase B (dst)
__global__ __launch_bounds__(256) void build_csr_dst(
    const unsigned* __restrict__ bkt, const int* __restrict__ cur,
    int* __restrict__ adj, int* __restrict__ cnt) {
    __shared__ int lc[512];
    int b = blockIdx.x, tid = threadIdx.x;
    lc[tid] = 0; lc[tid + 256] = 0;
    __syncthreads();
    int n = cur[b]; if (n > CAPB_D) n = CAPB_D;
    int n0 = b << BSH;
    const unsigned* base = bkt + (size_t)b * CAPB_D;
    for (int i = tid; i < n; i += 256) {
        unsigned r = base[i];
        int d = r >> 16, s = r & 0xffff;
        int sl = atomicAdd(&lc[d - n0], 1);
        if (sl < CAPD) adj[d * CAPD + sl] = s;
    }
    __syncthreads();
    int g0 = n0 + tid;
    if (g0 < Nn) cnt[g0] = lc[tid];
    g0 += 256;
    if (g0 < Nn) cnt[g0] = lc[tid + 256];
}

// Phase B (src): unmasked dst -> row front, masked dst -> row back.
__global__ __launch_bounds__(256) void build_csr_src(
    const unsigned* __restrict__ bkt, const int* __restrict__ cur,
    const void* __restrict__ mask, const int* __restrict__ flag,
    int* __restrict__ adj, int* __restrict__ cnt_u, int* __restrict__ cnt_m) {
    __shared__ int lu[512], lm[512];
    int b = blockIdx.x, tid = threadIdx.x;
    lu[tid] = 0; lu[tid + 256] = 0; lm[tid] = 0; lm[tid + 256] = 0;
    __syncthreads();
    int fmt = *flag;
    int n = cur[b]; if (n > CAPB_S) n = CAPB_S;
    int n0 = b << BSH;
    const unsigned* base = bkt + (size_t)b * CAPB_S;
    for (int i = tid; i < n; i += 256) {
        unsigned r = base[i];
        int s = r >> 16, d = r & 0xffff;
        if (read_mask(mask, d, fmt)) {
            int sl = atomicAdd(&lm[s - n0], 1);
            if (sl < CAPS) adj[s * CAPS + (CAPS - 1 - sl)] = d;
        } else {
            int sl = atomicAdd(&lu[s - n0], 1);
            if (sl < CAPS) adj[s * CAPS + sl] = d;
        }
    }
    __syncthreads();
    int g0 = n0 + tid;
    if (g0 < Nn) { cnt_u[g0] = lu[tid]; cnt_m[g0] = lm[tid]; }
    g0 += 256;
    if (g0 < Nn) { cnt_u[g0] = lu[tid + 256]; cnt_m[g0] = lm[tid + 256]; }
}

__global__ void build_unmasked(const void* __restrict__ mask,
                               const int* __restrict__ flag,
                               int* n_un, int* __restrict__ ulist) {
    int i = blockIdx.x * blockDim.x + threadIdx.x;
    if (i < Nn) {
        if (!read_mask(mask, i, *flag)) {
            int p = atomicAdd(n_un, 1);
            ulist[p] = i;
        }
    }
}

// ---------------------------------------------------------------------------
// GEMM1 v5: h1[n, j] = (sum_k feat[n,k] * W1[k,j]) * norm_src[n], bf16 out.
// 64x128 block tile (782 blocks; feat read ONCE), 8x4 thread tile.
// A staged as float4 k-chunks -> b128 reads, 2 distinct addrs/wave (free).
// B read at c0=(tid&31)*4 (contiguous 512B/wave: measured conflict-free).
#define G1_ROWS 64
#define G1_KT 32
__global__ __launch_bounds__(256) void gemm1(
    const float* __restrict__ feat, const float* __restrict__ W1,
    const int* __restrict__ cnt_src, unsigned* __restrict__ h1b) {
    __shared__ float4 lA4[G1_ROWS][8];   // 8KB
    __shared__ float lB[G1_KT][HID];     // 16KB
    const int tid = threadIdx.x;
    const int row0 = blockIdx.x * G1_ROWS;
    const int r0 = (tid >> 5) * 8;   // 8 row-groups of 8
    const int c0 = (tid & 31) * 4;   // 32 col-groups of 4

    float4 acc[8];
#pragma unroll
    for (int i = 0; i < 8; i++) acc[i] = make_float4(0.f, 0.f, 0.f, 0.f);

    for (int k0 = 0; k0 < INF_; k0 += G1_KT) {
        // stage A: 64 rows x 8 chunks = 512 float4, 2/thread
#pragma unroll
        for (int p = 0; p < 2; p++) {
            int idx = tid + p * 256;
            int r = idx >> 3, c = idx & 7;
            int grow = row0 + r;
            float4 v = make_float4(0.f, 0.f, 0.f, 0.f);
            if (grow < Nn)
                v = *(const float4*)(feat + (size_t)grow * INF_ + k0 + c * 4);
            lA4[r][c] = v;
        }
        // stage B: 32 k x 128 cols = 1024 float4, 4/thread
#pragma unroll
        for (int p = 0; p < 4; p++) {
            int idx = tid + p * 256;
            int kb = idx >> 5, c4 = idx & 31;
            *(float4*)(&lB[kb][c4 * 4]) =
                *(const float4*)(W1 + (size_t)(k0 + kb) * HID + c4 * 4);
        }
        __syncthreads();
#pragma unroll
        for (int k4 = 0; k4 < 8; k4++) {
            float4 av[8];
#pragma unroll
            for (int i = 0; i < 8; i++) av[i] = lA4[r0 + i][k4];
#pragma unroll
            for (int kk = 0; kk < 4; kk++) {
                float4 bv = *(const float4*)(&lB[k4 * 4 + kk][c0]);
#pragma unroll
                for (int i = 0; i < 8; i++) {
                    float a = kk == 0 ? av[i].x
                            : kk == 1 ? av[i].y
                            : kk == 2 ? av[i].z : av[i].w;
                    acc[i].x += a * bv.x; acc[i].y += a * bv.y;
                    acc[i].z += a * bv.z; acc[i].w += a * bv.w;
                }
            }
        }
        __syncthreads();
    }
#pragma unroll
    for (int i = 0; i < 8; i++) {
        int grow = row0 + r0 + i;
        if (grow < Nn) {
            int dg = cnt_src[grow];
            float nrm = rsqrtf((float)(dg > 1 ? dg : 1));
            uint2 pk;
            pk.x = f2bf2(acc[i].x * nrm, acc[i].y * nrm);
            pk.y = f2bf2(acc[i].z * nrm, acc[i].w * nrm);
            *(uint2*)(h1b + (size_t)grow * 64 + (c0 >> 1)) = pk;
        }
    }
}

// ---------------------------------------------------------------------------
// agg1: x1[i,:] = relu( norm_dst[i] * sum_{e: dst=i} h1[src_e,:] + b1 )
// h1 rows are bf16 (256B). 16 nodes/block x 16 lanes; uint4 (8 bf16) gathers.
__global__ __launch_bounds__(256) void agg_relu1(
    const uint4* __restrict__ h1b, const int* __restrict__ adj_dst,
    const int* __restrict__ cnt_dst, const float4* __restrict__ b1,
    float4* __restrict__ x1) {
    int node = blockIdx.x * 16 + (threadIdx.x >> 4);
    int l = threadIdx.x & 15;
    int dg = cnt_dst[node];
    int cnt = dg < CAPD ? dg : CAPD;
    const int* lst = adj_dst + (size_t)node * CAPD;
    float s0 = 0.f, s1 = 0.f, s2 = 0.f, s3 = 0.f;
    float s4 = 0.f, s5 = 0.f, s6 = 0.f, s7 = 0.f;
    int e = 0;
    for (; e + 8 <= cnt; e += 8) {
        uint4 u[8];
#pragma unroll
        for (int q = 0; q < 8; q++) u[q] = h1b[(size_t)lst[e + q] * 16 + l];
#pragma unroll
        for (int q = 0; q < 8; q++) {
            s0 += bf_lo(u[q].x); s1 += bf_hi(u[q].x);
            s2 += bf_lo(u[q].y); s3 += bf_hi(u[q].y);
            s4 += bf_lo(u[q].z); s5 += bf_hi(u[q].z);
            s6 += bf_lo(u[q].w); s7 += bf_hi(u[q].w);
        }
    }
    for (; e < cnt; e++) {
        uint4 u = h1b[(size_t)lst[e] * 16 + l];
        s0 += bf_lo(u.x); s1 += bf_hi(u.x);
        s2 += bf_lo(u.y); s3 += bf_hi(u.y);
        s4 += bf_lo(u.z); s5 += bf_hi(u.z);
        s6 += bf_lo(u.w); s7 += bf_hi(u.w);
    }
    float nrm = rsqrtf((float)(dg > 1 ? dg : 1));
    float4 bb0 = b1[l * 2], bb1 = b1[l * 2 + 1];
    float4 v0, v1;
    v0.x = fmaxf(s0 * nrm + bb0.x, 0.f);
    v0.y = fmaxf(s1 * nrm + bb0.y, 0.f);
    v0.z = fmaxf(s2 * nrm + bb0.z, 0.f);
    v0.w = fmaxf(s3 * nrm + bb0.w, 0.f);
    v1.x = fmaxf(s4 * nrm + bb1.x, 0.f);
    v1.y = fmaxf(s5 * nrm + bb1.y, 0.f);
    v1.z = fmaxf(s6 * nrm + bb1.z, 0.f);
    v1.w = fmaxf(s7 * nrm + bb1.w, 0.f);
    x1[(size_t)node * 32 + l * 2] = v0;
    x1[(size_t)node * 32 + l * 2 + 1] = v1;
}

// ---------------------------------------------------------------------------
// GEMM2: W2 (20KB) fully in LDS; one thread = one row; bf16 output rows.
__global__ __launch_bounds__(256) void gemm2(
    const float4* __restrict__ x1, const float4* __restrict__ W2,
    const int* __restrict__ cnt_src, unsigned* __restrict__ h2b) {
    __shared__ float lw[HID * NC];   // 20KB
    int tid = threadIdx.x;
    for (int i = tid; i < HID * NC / 4; i += 256)
        ((float4*)lw)[i] = W2[i];
    __syncthreads();
    int r = blockIdx.x * 256 + tid;
    if (r >= Nn) return;
    const float4* xr = x1 + (size_t)r * 32;
    float4 acc[10];
#pragma unroll
    for (int j = 0; j < 10; j++) acc[j] = make_float4(0.f, 0.f, 0.f, 0.f);
    for (int k4 = 0; k4 < 32; k4++) {
        float4 xv = xr[k4];
#pragma unroll
        for (int s = 0; s < 4; s++) {
            float x = s == 0 ? xv.x : (s == 1 ? xv.y : (s == 2 ? xv.z : xv.w));
            const float4* wrow = (const float4*)(lw + (k4 * 4 + s) * NC);
#pragma unroll
            for (int j = 0; j < 10; j++) {
                float4 w = wrow[j];
                acc[j].x += x * w.x; acc[j].y += x * w.y;
                acc[j].z += x * w.z; acc[j].w += x * w.w;
            }
        }
    }
    int dg = cnt_src[r];
    float nrm = rsqrtf((float)(dg > 1 ? dg : 1));
    uint2* out = (uint2*)(h2b + (size_t)r * 20);
#pragma unroll
    for (int j = 0; j < 10; j++) {
        uint2 pk;
        pk.x = f2bf2(acc[j].x * nrm, acc[j].y * nrm);
        pk.y = f2bf2(acc[j].z * nrm, acc[j].w * nrm);
        out[j] = pk;
    }
}

// ---------------------------------------------------------------------------
// agg2: out_x[i,c] = norm_dst[i] * sum_{e: dst=i} h2[src_e,c] + b2[c]
// h2 rows bf16 (80B). 32 nodes x 10 lanes; uint2 (4 bf16) gathers.
__global__ __launch_bounds__(320) void agg2(
    const uint2* __restrict__ h2b, const int* __restrict__ adj_dst,
    const int* __restrict__ cnt_dst, const float4* __restrict__ b2,
    float4* __restrict__ out_x) {
    int node = blockIdx.x * 32 + threadIdx.x / 10;
    int l = threadIdx.x % 10;
    if (node >= Nn) return;
    int dg = cnt_dst[node];
    int cnt = dg < CAPD ? dg : CAPD;
    const int* lst = adj_dst + (size_t)node * CAPD;
    float s0 = 0.f, s1 = 0.f, s2 = 0.f, s3 = 0.f;
    int e = 0;
    for (; e + 8 <= cnt; e += 8) {
        uint2 u[8];
#pragma unroll
        for (int q = 0; q < 8; q++) u[q] = h2b[(size_t)lst[e + q] * 10 + l];
#pragma unroll
        for (int q = 0; q < 8; q++) {
            s0 += bf_lo(u[q].x); s1 += bf_hi(u[q].x);
            s2 += bf_lo(u[q].y); s3 += bf_hi(u[q].y);
        }
    }
    for (; e + 4 <= cnt; e += 4) {
        uint2 u[4];
#pragma unroll
        for (int q = 0; q < 4; q++) u[q] = h2b[(size_t)lst[e + q] * 10 + l];
#pragma unroll
        for (int q = 0; q < 4; q++) {
            s0 += bf_lo(u[q].x); s1 += bf_hi(u[q].x);
            s2 += bf_lo(u[q].y); s3 += bf_hi(u[q].y);
        }
    }
    for (; e < cnt; e++) {
        uint2 u = h2b[(size_t)lst[e] * 10 + l];
        s0 += bf_lo(u.x); s1 += bf_hi(u.x);
        s2 += bf_lo(u.y); s3 += bf_hi(u.y);
    }
    float nrm = rsqrtf((float)(dg > 1 ? dg : 1));
    float4 bb = b2[l];
    float4 v;
    v.x = s0 * nrm + bb.x;
    v.y = s1 * nrm + bb.y;
    v.z = s2 * nrm + bb.z;
    v.w = s3 * nrm + bb.w;
    out_x[(size_t)node * 10 + l] = v;
}

// ---------------------------------------------------------------------------
// LPA. y_t[u] = S_const[u] + sum_{unmasked nbr v} y_{t-1}[v]; y_1 == S_const.
// Iteration state in bf16 (4MB buffers, L2-resident); S_const fp32; final
// step writes fp32 into out_y. Masked rows of out_y = labels (lpa_init).
__global__ void lpa_init(const float* __restrict__ labels, const void* mask,
                         const int* __restrict__ flag, float* __restrict__ out_y) {
    int g = blockIdx.x * blockDim.x + threadIdx.x;
    if (g >= Nn * NC) return;
    int node = g / NC;
    if (read_mask(mask, node, *flag)) out_y[g] = labels[g];
}

__global__ __launch_bounds__(320) void lpa_const(
    const float4* __restrict__ labels, const int* __restrict__ n_un,
    const int* __restrict__ ulist, const int* __restrict__ adj_s,
    const int* __restrict__ cnt_m, float4* __restrict__ sconst,
    uint2* __restrict__ y1b) {
    int g = blockIdx.x * 32 + threadIdx.x / 10;
    int l = threadIdx.x % 10;
    if (g >= *n_un) return;
    int u = ulist[g];
    int cm = cnt_m[u];
    int cnt = cm < CAPS ? cm : CAPS;
    const int* lst = adj_s + (size_t)u * CAPS + (CAPS - cnt);
    float4 s = make_float4(0.f, 0.f, 0.f, 0.f);
    int e = 0;
    for (; e + 8 <= cnt; e += 8) {
        float4 v[8];
#pragma unroll
        for (int q = 0; q < 8; q++) v[q] = labels[(size_t)lst[e + q] * 10 + l];
#pragma unroll
        for (int q = 0; q < 8; q++) {
            s.x += v[q].x; s.y += v[q].y; s.z += v[q].z; s.w += v[q].w;
        }
    }
    for (; e + 4 <= cnt; e += 4) {
        float4 v[4];
#pragma unroll
        for (int q = 0; q < 4; q++) v[q] = labels[(size_t)lst[e + q] * 10 + l];
#pragma unroll
        for (int q = 0; q < 4; q++) {
            s.x += v[q].x; s.y += v[q].y; s.z += v[q].z; s.w += v[q].w;
        }
    }
    for (; e < cnt; e++) {
        float4 a = labels[(size_t)lst[e] * 10 + l];
        s.x += a.x; s.y += a.y; s.z += a.z; s.w += a.w;
    }
    sconst[(size_t)u * 10 + l] = s;
    uint2 pk; pk.x = f2bf2(s.x, s.y); pk.y = f2bf2(s.z, s.w);
    y1b[(size_t)u * 10 + l] = pk;
}

__global__ __launch_bounds__(320) void lpa_mid(
    const uint2* __restrict__ ycur, const int* __restrict__ n_un,
    const int* __restrict__ ulist, const int* __restrict__ adj_s,
    const int* __restrict__ cnt_u, const float4* __restrict__ sconst,
    uint2* __restrict__ ynext) {
    int g = blockIdx.x * 32 + threadIdx.x / 10;
    int l = threadIdx.x % 10;
    if (g >= *n_un) return;
    int u = ulist[g];
    int cu = cnt_u[u];
    int cnt = cu < CAPS ? cu : CAPS;
    const int* lst = adj_s + (size_t)u * CAPS;
    float4 s = sconst[(size_t)u * 10 + l];
    int e = 0;
    for (; e + 8 <= cnt; e += 8) {
        uint2 v[8];
#pragma unroll
        for (int q = 0; q < 8; q++) v[q] = ycur[(size_t)lst[e + q] * 10 + l];
#pragma unroll
        for (int q = 0; q < 8; q++) {
            s.x += bf_lo(v[q].x); s.y += bf_hi(v[q].x);
            s.z += bf_lo(v[q].y); s.w += bf_hi(v[q].y);
        }
    }
    for (; e + 4 <= cnt; e += 4) {
        uint2 v[4];
#pragma unroll
        for (int q = 0; q < 4; q++) v[q] = ycur[(size_t)lst[e + q] * 10 + l];
#pragma unroll
        for (int q = 0; q < 4; q++) {
            s.x += bf_lo(v[q].x); s.y += bf_hi(v[q].x);
            s.z += bf_lo(v[q].y); s.w += bf_hi(v[q].y);
        }
    }
    for (; e < cnt; e++) {
        uint2 v = ycur[(size_t)lst[e] * 10 + l];
        s.x += bf_lo(v.x); s.y += bf_hi(v.x);
        s.z += bf_lo(v.y); s.w += bf_hi(v.y);
    }
    uint2 pk; pk.x = f2bf2(s.x, s.y); pk.y = f2bf2(s.z, s.w);
    ynext[(size_t)u * 10 + l] = pk;
}

__global__ __launch_bounds__(320) void lpa_last(
    const uint2* __restrict__ ycur, const int* __restrict__ n_un,
    const int* __restrict__ ulist, const int* __restrict__ adj_s,
    const int* __restrict__ cnt_u, const float4* __restrict__ sconst,
    float4* __restrict__ out_y) {
    int g = blockIdx.x * 32 + threadIdx.x / 10;
    int l = threadIdx.x % 10;
    if (g >= *n_un) return;
    int u = ulist[g];
    int cu = cnt_u[u];
    int cnt = cu < CAPS ? cu : CAPS;
    const int* lst = adj_s + (size_t)u * CAPS;
    float4 s = sconst[(size_t)u * 10 + l];
    int e = 0;
    for (; e + 8 <= cnt; e += 8) {
        uint2 v[8];
#pragma unroll
        for (int q = 0; q < 8; q++) v[q] = ycur[(size_t)lst[e + q] * 10 + l];
#pragma unroll
        for (int q = 0; q < 8; q++) {
            s.x += bf_lo(v[q].x); s.y += bf_hi(v[q].x);
            s.z += bf_lo(v[q].y); s.w += bf_hi(v[q].y);
        }
    }
    for (; e + 4 <= cnt; e += 4) {
        uint2 v[4];
#pragma unroll
        for (int q = 0; q < 4; q++) v[q] = ycur[(size_t)lst[e + q] * 10 + l];
#pragma unroll
        for (int q = 0; q < 4; q++) {
            s.x += bf_lo(v[q].x); s.y += bf_hi(v[q].x);
            s.z += bf_lo(v[q].y); s.w += bf_hi(v[q].y);
        }
    }
    for (; e < cnt; e++) {
        uint2 v = ycur[(size_t)lst[e] * 10 + l];
        s.x += bf_lo(v.x); s.y += bf_hi(v.x);
        s.z += bf_lo(v.y); s.w += bf_hi(v.y);
    }
    out_y[(size_t)u * 10 + l] = s;
}

// ---------------------------------------------------------------------------
extern "C" void kernel_launch(void* const* d_in, const int* in_sizes, int n_in,
                              void* d_out, int out_size, void* d_ws, size_t ws_size,
                              hipStream_t stream) {
    const float* feat   = (const float*)d_in[0];
    const float* labels = (const float*)d_in[1];
    const void*  mask   = d_in[2];
    const int*   src    = (const int*)d_in[3];
    const int*   dst    = (const int*)d_in[4];
    const float* W1     = (const float*)d_in[5];
    const float* b1     = (const float*)d_in[6];
    const float* W2     = (const float*)d_in[7];
    const float* b2     = (const float*)d_in[8];

    float* out_x = (float*)d_out;
    float* out_y = out_x + (size_t)Nn * NC;

    char* ws = (char*)d_ws;
    size_t off = 0;
    auto alloc = [&](size_t bytes) -> void* {
        void* p = ws + off;
        off += (bytes + 255) & ~(size_t)255;
        return p;
    };
    // --- zeroed header ---
    int* flag    = (int*)alloc(256);   // flag[0]=fmt, flag[1]=n_un
    int* n_un    = flag + 1;
    int* cnt_src = (int*)alloc((size_t)Nn * 4);
    int* cur_d   = (int*)alloc(512);
    int* cur_s   = (int*)alloc(512);
    size_t zero_bytes = off;
    // --- non-zeroed ---
    int* cnt_dst = (int*)alloc((size_t)Nn * 4);
    int* cnt_u   = (int*)alloc((size_t)Nn * 4);
    int* cnt_m   = (int*)alloc((size_t)Nn * 4);
    int* ulist   = (int*)alloc((size_t)Nn * 4);
    // --- big buffers; bucket bins alias h1b (dead before gemm1 writes) ---
    char* uni = (char*)alloc((size_t)Nn * HID * 2);        // 12.8MB union
    unsigned* bkt_d = (unsigned*)uni;                       // ~4.0MB
    unsigned* bkt_s = (unsigned*)(uni + (size_t)NB * CAPB_D * 4); // ~2.4MB
    unsigned* h1b = (unsigned*)uni;                         // bf16 h1
    float* x1 = (float*)alloc((size_t)Nn * HID * 4);
    int* adj_s   = (int*)alloc((size_t)Nn * CAPS * 4);
    int* adj_dst = (int*)alloc((size_t)Nn * CAPD * 4);
    unsigned* h2b = (unsigned*)alloc((size_t)Nn * NC * 2);  // bf16 h2
    float* sconst = (float*)alloc((size_t)Nn * NC * 4);
    uint2* y1b = (uint2*)alloc((size_t)Nn * NC * 2);        // bf16 y ping
    uint2* y2b = (uint2*)alloc((size_t)Nn * NC * 2);        // bf16 y pong

    hipMemsetAsync(d_ws, 0, zero_bytes, stream);

    detect_fmt<<<49, 256, 0, stream>>>((const unsigned int*)mask, flag);
    bin_edges<<<NBLK, 256, 0, stream>>>(src, dst, mask, flag, cnt_src,
                                        cur_d, cur_s, bkt_d, bkt_s);
    build_csr_dst<<<NB, 256, 0, stream>>>(bkt_d, cur_d, adj_dst, cnt_dst);
    build_csr_src<<<NB, 256, 0, stream>>>(bkt_s, cur_s, mask, flag,
                                          adj_s, cnt_u, cnt_m);
    build_unmasked<<<196, 256, 0, stream>>>(mask, flag, n_un, ulist);

    gemm1<<<(Nn + G1_ROWS - 1) / G1_ROWS, 256, 0, stream>>>(feat, W1, cnt_src, h1b);
    agg_relu1<<<Nn / 16, 256, 0, stream>>>((const uint4*)h1b, adj_dst, cnt_dst,
                                           (const float4*)b1, (float4*)x1);
    gemm2<<<196, 256, 0, stream>>>((const float4*)x1, (const float4*)W2,
                                   cnt_src, h2b);
    agg2<<<(Nn + 31) / 32, 320, 0, stream>>>((const uint2*)h2b, adj_dst, cnt_dst,
                                             (const float4*)b2, (float4*)out_x);

    lpa_init<<<(Nn * NC + 255) / 256, 256, 0, stream>>>(labels, mask, flag, out_y);
    lpa_const<<<(Nn + 31) / 32, 320, 0, stream>>>(
        (const float4*)labels, n_un, ulist, adj_s, cnt_m, (float4*)sconst, y1b);
    const uint2* cur = y1b;
    for (int i = 0; i < 8; i++) {          // iterations 2..9
        uint2* nxt = (i & 1) ? y1b : y2b;
        lpa_mid<<<(Nn + 31) / 32, 320, 0, stream>>>(
            cur, n_un, ulist, adj_s, cnt_u, (const float4*)sconst, nxt);
        cur = nxt;
    }
    lpa_last<<<(Nn + 31) / 32, 320, 0, stream>>>(   // iteration 10
        cur, n_un, ulist, adj_s, cnt_u, (const float4*)sconst, (float4*)out_y);
}

// Round 10
// 398.164 us; speedup vs baseline: 1.1690x; 1.0823x over previous
//
#include <hip/hip_runtime.h>

#define Nn 50000
#define Ee 800000
#define INF_ 256
#define HID 128
#define NC 40
#define CAPD 48      // adj_dst row capacity (Poisson(16) tail @48 ~1e-11)
#define CAPS 48      // adj_s row capacity (u-list front, m-list back)
#define LPA_ITERS 10
#define NB 98        // node buckets of 512
#define BSH 9
#define EPB 2048     // edges per bin_edges block
#define NBLK ((Ee + EPB - 1) / EPB)   // 391
#define CAPB_D 10240 // per-bucket bin capacity, dst direction (mean 8163)
#define CAPB_S 6144  // per-bucket bin capacity, src/unmasked (mean ~4081)

typedef __attribute__((ext_vector_type(8))) short bfrag;
typedef __attribute__((ext_vector_type(4))) float ffrag;

// ---- bf16 helpers (fp32 math, bf16 storage; RNE rounding) ------------------
__device__ inline unsigned f2bf2(float a, float b) {
    unsigned ua = __float_as_uint(a); ua += 0x7FFFu + ((ua >> 16) & 1u);
    unsigned ub = __float_as_uint(b); ub += 0x7FFFu + ((ub >> 16) & 1u);
    return (ua >> 16) | (ub & 0xFFFF0000u);
}
__device__ inline unsigned short f2bf(float a) {
    unsigned ua = __float_as_uint(a); ua += 0x7FFFu + ((ua >> 16) & 1u);
    return (unsigned short)(ua >> 16);
}
__device__ inline float bf_lo(unsigned u) { return __uint_as_float(u << 16); }
__device__ inline float bf_hi(unsigned u) { return __uint_as_float(u & 0xFFFF0000u); }

// ---------------------------------------------------------------------------
__global__ void detect_fmt(const unsigned int* __restrict__ m, int* flag) {
    int i = blockIdx.x * blockDim.x + threadIdx.x;
    if (i < 12500) {
        if (m[i] > 1u) atomicOr(flag, 1);
    }
}

__device__ inline bool read_mask(const void* mask, int node, int fmt) {
    if (fmt) return ((const unsigned char*)mask)[node] != 0;
    return ((const int*)mask)[node] != 0;
}

// ---------------------------------------------------------------------------
// Single-pass edge binning, both directions, one edge read. Fixed-capacity
// global bins (no prepass); LDS staging -> coalesced writebacks.
__global__ __launch_bounds__(256) void bin_edges(
    const int* __restrict__ src, const int* __restrict__ dst,
    const void* __restrict__ mask, const int* __restrict__ flag,
    int* __restrict__ cnt_src,
    int* __restrict__ cur_d, int* __restrict__ cur_s,
    unsigned* __restrict__ bkt_d, unsigned* __restrict__ bkt_s) {
    __shared__ unsigned stage_d[EPB];
    __shared__ unsigned stage_s[EPB];
    __shared__ int hd[NB], od[NB + 1], cd[NB], gd_[NB];
    __shared__ int hs[NB], os_[NB + 1], cs_[NB], gs_[NB];
    int tid = threadIdx.x;
    int e0 = blockIdx.x * EPB;
    int fmt = *flag;
    if (tid < NB) { hd[tid] = 0; hs[tid] = 0; }
    __syncthreads();

    int rs[EPB / 256], rd[EPB / 256];
    unsigned um = 0;  // bit k: src unmasked
#pragma unroll
    for (int k = 0; k < EPB / 256; k++) {
        int e = e0 + tid + k * 256;
        rs[k] = -1; rd[k] = -1;
        if (e < Ee) {
            int s = src[e], d = dst[e];
            rs[k] = s; rd[k] = d;
            atomicAdd(&cnt_src[s], 1);
            atomicAdd(&hd[d >> BSH], 1);
            if (!read_mask(mask, s, fmt)) {
                um |= (1u << k);
                atomicAdd(&hs[s >> BSH], 1);
            }
        }
    }
    __syncthreads();
    if (tid == 0) {
        int run = 0;
        for (int b = 0; b < NB; b++) { od[b] = run; run += hd[b]; }
        od[NB] = run;
        run = 0;
        for (int b = 0; b < NB; b++) { os_[b] = run; run += hs[b]; }
        os_[NB] = run;
    }
    __syncthreads();
    if (tid < NB) {
        gd_[tid] = hd[tid] ? atomicAdd(&cur_d[tid], hd[tid]) : 0;
        gs_[tid] = hs[tid] ? atomicAdd(&cur_s[tid], hs[tid]) : 0;
        cd[tid] = od[tid];
        cs_[tid] = os_[tid];
    }
    __syncthreads();
#pragma unroll
    for (int k = 0; k < EPB / 256; k++) {
        if (rd[k] >= 0) {
            int p = atomicAdd(&cd[rd[k] >> BSH], 1);
            stage_d[p] = ((unsigned)rd[k] << 16) | (unsigned)rs[k];
            if (um & (1u << k)) {
                int q = atomicAdd(&cs_[rs[k] >> BSH], 1);
                stage_s[q] = ((unsigned)rs[k] << 16) | (unsigned)rd[k];
            }
        }
    }
    __syncthreads();
    int totd = od[NB];
    for (int i = tid; i < totd; i += 256) {
        int lo = 0, hi = NB;
        while (hi - lo > 1) {
            int mid = (lo + hi) >> 1;
            if (od[mid] <= i) lo = mid; else hi = mid;
        }
        int pos = gd_[lo] + (i - od[lo]);
        if (pos < CAPB_D) bkt_d[(size_t)lo * CAPB_D + pos] = stage_d[i];
    }
    int tots = os_[NB];
    for (int i = tid; i < tots; i += 256) {
        int lo = 0, hi = NB;
        while (hi - lo > 1) {
            int mid = (lo + hi) >> 1;
            if (os_[mid] <= i) lo = mid; else hi = mid;
        }
        int pos = gs_[lo] + (i - os_[lo]);
        if (pos < CAPB_S) bkt_s[(size_t)lo * CAPB_S + pos] = stage_s[i];
    }
}

// Phase B (dst)
__global__ __launch_bounds__(256) void build_csr_dst(
    const unsigned* __restrict__ bkt, const int* __restrict__ cur,
    int* __restrict__ adj, int* __restrict__ cnt) {
    __shared__ int lc[512];
    int b = blockIdx.x, tid = threadIdx.x;
    lc[tid] = 0; lc[tid + 256] = 0;
    __syncthreads();
    int n = cur[b]; if (n > CAPB_D) n = CAPB_D;
    int n0 = b << BSH;
    const unsigned* base = bkt + (size_t)b * CAPB_D;
    for (int i = tid; i < n; i += 256) {
        unsigned r = base[i];
        int d = r >> 16, s = r & 0xffff;
        int sl = atomicAdd(&lc[d - n0], 1);
        if (sl < CAPD) adj[d * CAPD + sl] = s;
    }
    __syncthreads();
    int g0 = n0 + tid;
    if (g0 < Nn) cnt[g0] = lc[tid];
    g0 += 256;
    if (g0 < Nn) cnt[g0] = lc[tid + 256];
}

// Phase B (src): unmasked dst -> row front, masked dst -> row back.
__global__ __launch_bounds__(256) void build_csr_src(
    const unsigned* __restrict__ bkt, const int* __restrict__ cur,
    const void* __restrict__ mask, const int* __restrict__ flag,
    int* __restrict__ adj, int* __restrict__ cnt_u, int* __restrict__ cnt_m) {
    __shared__ int lu[512], lm[512];
    int b = blockIdx.x, tid = threadIdx.x;
    lu[tid] = 0; lu[tid + 256] = 0; lm[tid] = 0; lm[tid + 256] = 0;
    __syncthreads();
    int fmt = *flag;
    int n = cur[b]; if (n > CAPB_S) n = CAPB_S;
    int n0 = b << BSH;
    const unsigned* base = bkt + (size_t)b * CAPB_S;
    for (int i = tid; i < n; i += 256) {
        unsigned r = base[i];
        int s = r >> 16, d = r & 0xffff;
        if (read_mask(mask, d, fmt)) {
            int sl = atomicAdd(&lm[s - n0], 1);
            if (sl < CAPS) adj[s * CAPS + (CAPS - 1 - sl)] = d;
        } else {
            int sl = atomicAdd(&lu[s - n0], 1);
            if (sl < CAPS) adj[s * CAPS + sl] = d;
        }
    }
    __syncthreads();
    int g0 = n0 + tid;
    if (g0 < Nn) { cnt_u[g0] = lu[tid]; cnt_m[g0] = lm[tid]; }
    g0 += 256;
    if (g0 < Nn) { cnt_u[g0] = lu[tid + 256]; cnt_m[g0] = lm[tid + 256]; }
}

__global__ void build_unmasked(const void* __restrict__ mask,
                               const int* __restrict__ flag,
                               int* n_un, int* __restrict__ ulist) {
    int i = blockIdx.x * blockDim.x + threadIdx.x;
    if (i < Nn) {
        if (!read_mask(mask, i, *flag)) {
            int p = atomicAdd(n_un, 1);
            ulist[p] = i;
        }
    }
}

// ---------------------------------------------------------------------------
// prep_w1t: W1 (fp32 [k][col]) -> W1t (bf16 [col][k]) once; 64KB output.
__global__ void prep_w1t(const float* __restrict__ W1,
                         unsigned short* __restrict__ W1t) {
    int c = blockIdx.x;      // 0..127
    int k = threadIdx.x;     // 0..255
    W1t[c * INF_ + k] = f2bf(W1[(size_t)k * HID + c]);
}

// ---------------------------------------------------------------------------
// GEMM1 v6 (MFMA): h1 = (feat @ W1) * norm_src, bf16 in/out via matrix cores.
// Block: 256 thr = 4 waves, 64 rows x 128 cols, 782 blocks. Per wave: one
// 16-row strip x 8 col-tiles of v_mfma_f32_16x16x32_bf16, K-loop of 8x32.
// Verified layouts: A[m=lane&15][k=quad*8+j]; B[k=quad*8+j][n=lane&15];
// C/D row=quad*4+reg, col=lane&15.
#define G1_ROWS 64
__global__ __launch_bounds__(256) void gemm1(
    const float* __restrict__ feat, const unsigned short* __restrict__ W1t,
    const int* __restrict__ cnt_src, unsigned short* __restrict__ h1b) {
    __shared__ unsigned short lA[G1_ROWS * 32];   // [row][k] bf16, 4KB
    __shared__ unsigned short lB[HID * 32];       // [col][k] bf16, 8KB
    const int tid = threadIdx.x;
    const int row0 = blockIdx.x * G1_ROWS;
    const int w = tid >> 6;
    const int l = tid & 63;
    const int lane15 = l & 15;
    const int quad = l >> 4;
    const int rw0 = w * 16;

    ffrag acc[8];
#pragma unroll
    for (int t = 0; t < 8; t++) acc[t] = (ffrag){0.f, 0.f, 0.f, 0.f};

    for (int k0 = 0; k0 < INF_; k0 += 32) {
        // stage A: 64 rows x 32 k fp32 -> bf16; 512 float4, 2/thread
#pragma unroll
        for (int p = 0; p < 2; p++) {
            int idx = tid + p * 256;
            int r = idx >> 3, c4 = idx & 7;
            int grow = row0 + r;
            float4 v = make_float4(0.f, 0.f, 0.f, 0.f);
            if (grow < Nn)
                v = *(const float4*)(feat + (size_t)grow * INF_ + k0 + c4 * 4);
            uint2 pk;
            pk.x = f2bf2(v.x, v.y);
            pk.y = f2bf2(v.z, v.w);
            *(uint2*)((char*)lA + r * 64 + c4 * 8) = pk;
        }
        // stage B: copy pre-transposed bf16; 512 uint4, 2/thread
#pragma unroll
        for (int p = 0; p < 2; p++) {
            int idx = tid + p * 256;
            int col = idx >> 2, q = idx & 3;
            uint4 v = *(const uint4*)((const char*)W1t + col * 512 + k0 * 2 + q * 16);
            *(uint4*)((char*)lB + col * 64 + q * 16) = v;
        }
        __syncthreads();
        int arow = rw0 + lane15;
        bfrag af = *(const bfrag*)((const char*)lA + arow * 64 + quad * 16);
#pragma unroll
        for (int t = 0; t < 8; t++) {
            int col = t * 16 + lane15;
            bfrag bf = *(const bfrag*)((const char*)lB + col * 64 + quad * 16);
            acc[t] = __builtin_amdgcn_mfma_f32_16x16x32_bf16(af, bf, acc[t], 0, 0, 0);
        }
        __syncthreads();
    }
    // epilogue: scale by norm_src, store bf16 (row-major)
    float nrm[4];
#pragma unroll
    for (int i = 0; i < 4; i++) {
        int grow = row0 + rw0 + quad * 4 + i;
        int dg = (grow < Nn) ? cnt_src[grow] : 1;
        nrm[i] = rsqrtf((float)(dg > 1 ? dg : 1));
    }
#pragma unroll
    for (int t = 0; t < 8; t++) {
#pragma unroll
        for (int i = 0; i < 4; i++) {
            int grow = row0 + rw0 + quad * 4 + i;
            if (grow < Nn)
                h1b[(size_t)grow * HID + t * 16 + lane15] = f2bf(acc[t][i] * nrm[i]);
        }
    }
}

// ---------------------------------------------------------------------------
// agg1: x1[i,:] = relu( norm_dst[i] * sum_{e: dst=i} h1[src_e,:] + b1 )
// h1 rows are bf16 (256B). 16 nodes/block x 16 lanes; uint4 (8 bf16) gathers.
__global__ __launch_bounds__(256) void agg_relu1(
    const uint4* __restrict__ h1b, const int* __restrict__ adj_dst,
    const int* __restrict__ cnt_dst, const float4* __restrict__ b1,
    float4* __restrict__ x1) {
    int node = blockIdx.x * 16 + (threadIdx.x >> 4);
    int l = threadIdx.x & 15;
    int dg = cnt_dst[node];
    int cnt = dg < CAPD ? dg : CAPD;
    const int* lst = adj_dst + (size_t)node * CAPD;
    float s0 = 0.f, s1 = 0.f, s2 = 0.f, s3 = 0.f;
    float s4 = 0.f, s5 = 0.f, s6 = 0.f, s7 = 0.f;
    int e = 0;
    for (; e + 8 <= cnt; e += 8) {
        uint4 u[8];
#pragma unroll
        for (int q = 0; q < 8; q++) u[q] = h1b[(size_t)lst[e + q] * 16 + l];
#pragma unroll
        for (int q = 0; q < 8; q++) {
            s0 += bf_lo(u[q].x); s1 += bf_hi(u[q].x);
            s2 += bf_lo(u[q].y); s3 += bf_hi(u[q].y);
            s4 += bf_lo(u[q].z); s5 += bf_hi(u[q].z);
            s6 += bf_lo(u[q].w); s7 += bf_hi(u[q].w);
        }
    }
    for (; e < cnt; e++) {
        uint4 u = h1b[(size_t)lst[e] * 16 + l];
        s0 += bf_lo(u.x); s1 += bf_hi(u.x);
        s2 += bf_lo(u.y); s3 += bf_hi(u.y);
        s4 += bf_lo(u.z); s5 += bf_hi(u.z);
        s6 += bf_lo(u.w); s7 += bf_hi(u.w);
    }
    float nrm = rsqrtf((float)(dg > 1 ? dg : 1));
    float4 bb0 = b1[l * 2], bb1 = b1[l * 2 + 1];
    float4 v0, v1;
    v0.x = fmaxf(s0 * nrm + bb0.x, 0.f);
    v0.y = fmaxf(s1 * nrm + bb0.y, 0.f);
    v0.z = fmaxf(s2 * nrm + bb0.z, 0.f);
    v0.w = fmaxf(s3 * nrm + bb0.w, 0.f);
    v1.x = fmaxf(s4 * nrm + bb1.x, 0.f);
    v1.y = fmaxf(s5 * nrm + bb1.y, 0.f);
    v1.z = fmaxf(s6 * nrm + bb1.z, 0.f);
    v1.w = fmaxf(s7 * nrm + bb1.w, 0.f);
    x1[(size_t)node * 32 + l * 2] = v0;
    x1[(size_t)node * 32 + l * 2 + 1] = v1;
}

// ---------------------------------------------------------------------------
// GEMM2: W2 (20KB) fully in LDS; one thread = one row; bf16 output rows.
__global__ __launch_bounds__(256) void gemm2(
    const float4* __restrict__ x1, const float4* __restrict__ W2,
    const int* __restrict__ cnt_src, unsigned* __restrict__ h2b) {
    __shared__ float lw[HID * NC];   // 20KB
    int tid = threadIdx.x;
    for (int i = tid; i < HID * NC / 4; i += 256)
        ((float4*)lw)[i] = W2[i];
    __syncthreads();
    int r = blockIdx.x * 256 + tid;
    if (r >= Nn) return;
    const float4* xr = x1 + (size_t)r * 32;
    float4 acc[10];
#pragma unroll
    for (int j = 0; j < 10; j++) acc[j] = make_float4(0.f, 0.f, 0.f, 0.f);
    for (int k4 = 0; k4 < 32; k4++) {
        float4 xv = xr[k4];
#pragma unroll
        for (int s = 0; s < 4; s++) {
            float x = s == 0 ? xv.x : (s == 1 ? xv.y : (s == 2 ? xv.z : xv.w));
            const float4* wrow = (const float4*)(lw + (k4 * 4 + s) * NC);
#pragma unroll
            for (int j = 0; j < 10; j++) {
                float4 w = wrow[j];
                acc[j].x += x * w.x; acc[j].y += x * w.y;
                acc[j].z += x * w.z; acc[j].w += x * w.w;
            }
        }
    }
    int dg = cnt_src[r];
    float nrm = rsqrtf((float)(dg > 1 ? dg : 1));
    uint2* out = (uint2*)(h2b + (size_t)r * 20);
#pragma unroll
    for (int j = 0; j < 10; j++) {
        uint2 pk;
        pk.x = f2bf2(acc[j].x * nrm, acc[j].y * nrm);
        pk.y = f2bf2(acc[j].z * nrm, acc[j].w * nrm);
        out[j] = pk;
    }
}

// ---------------------------------------------------------------------------
// agg2: out_x[i,c] = norm_dst[i] * sum_{e: dst=i} h2[src_e,c] + b2[c]
// h2 rows bf16 (80B). 32 nodes x 10 lanes; uint2 (4 bf16) gathers.
__global__ __launch_bounds__(320) void agg2(
    const uint2* __restrict__ h2b, const int* __restrict__ adj_dst,
    const int* __restrict__ cnt_dst, const float4* __restrict__ b2,
    float4* __restrict__ out_x) {
    int node = blockIdx.x * 32 + threadIdx.x / 10;
    int l = threadIdx.x % 10;
    if (node >= Nn) return;
    int dg = cnt_dst[node];
    int cnt = dg < CAPD ? dg : CAPD;
    const int* lst = adj_dst + (size_t)node * CAPD;
    float s0 = 0.f, s1 = 0.f, s2 = 0.f, s3 = 0.f;
    int e = 0;
    for (; e + 8 <= cnt; e += 8) {
        uint2 u[8];
#pragma unroll
        for (int q = 0; q < 8; q++) u[q] = h2b[(size_t)lst[e + q] * 10 + l];
#pragma unroll
        for (int q = 0; q < 8; q++) {
            s0 += bf_lo(u[q].x); s1 += bf_hi(u[q].x);
            s2 += bf_lo(u[q].y); s3 += bf_hi(u[q].y);
        }
    }
    for (; e + 4 <= cnt; e += 4) {
        uint2 u[4];
#pragma unroll
        for (int q = 0; q < 4; q++) u[q] = h2b[(size_t)lst[e + q] * 10 + l];
#pragma unroll
        for (int q = 0; q < 4; q++) {
            s0 += bf_lo(u[q].x); s1 += bf_hi(u[q].x);
            s2 += bf_lo(u[q].y); s3 += bf_hi(u[q].y);
        }
    }
    for (; e < cnt; e++) {
        uint2 u = h2b[(size_t)lst[e] * 10 + l];
        s0 += bf_lo(u.x); s1 += bf_hi(u.x);
        s2 += bf_lo(u.y); s3 += bf_hi(u.y);
    }
    float nrm = rsqrtf((float)(dg > 1 ? dg : 1));
    float4 bb = b2[l];
    float4 v;
    v.x = s0 * nrm + bb.x;
    v.y = s1 * nrm + bb.y;
    v.z = s2 * nrm + bb.z;
    v.w = s3 * nrm + bb.w;
    out_x[(size_t)node * 10 + l] = v;
}

// ---------------------------------------------------------------------------
// LPA. y_t[u] = S_const[u] + sum_{unmasked nbr v} y_{t-1}[v]; y_1 == S_const.
// Iteration state in bf16 (4MB buffers, L2-resident); S_const fp32; final
// step writes fp32 into out_y. Masked rows of out_y = labels (lpa_init).
__global__ void lpa_init(const float* __restrict__ labels, const void* mask,
                         const int* __restrict__ flag, float* __restrict__ out_y) {
    int g = blockIdx.x * blockDim.x + threadIdx.x;
    if (g >= Nn * NC) return;
    int node = g / NC;
    if (read_mask(mask, node, *flag)) out_y[g] = labels[g];
}

__global__ __launch_bounds__(320) void lpa_const(
    const float4* __restrict__ labels, const int* __restrict__ n_un,
    const int* __restrict__ ulist, const int* __restrict__ adj_s,
    const int* __restrict__ cnt_m, float4* __restrict__ sconst,
    uint2* __restrict__ y1b) {
    int g = blockIdx.x * 32 + threadIdx.x / 10;
    int l = threadIdx.x % 10;
    if (g >= *n_un) return;
    int u = ulist[g];
    int cm = cnt_m[u];
    int cnt = cm < CAPS ? cm : CAPS;
    const int* lst = adj_s + (size_t)u * CAPS + (CAPS - cnt);
    float4 s = make_float4(0.f, 0.f, 0.f, 0.f);
    int e = 0;
    for (; e + 8 <= cnt; e += 8) {
        float4 v[8];
#pragma unroll
        for (int q = 0; q < 8; q++) v[q] = labels[(size_t)lst[e + q] * 10 + l];
#pragma unroll
        for (int q = 0; q < 8; q++) {
            s.x += v[q].x; s.y += v[q].y; s.z += v[q].z; s.w += v[q].w;
        }
    }
    for (; e + 4 <= cnt; e += 4) {
        float4 v[4];
#pragma unroll
        for (int q = 0; q < 4; q++) v[q] = labels[(size_t)lst[e + q] * 10 + l];
#pragma unroll
        for (int q = 0; q < 4; q++) {
            s.x += v[q].x; s.y += v[q].y; s.z += v[q].z; s.w += v[q].w;
        }
    }
    for (; e < cnt; e++) {
        float4 a = labels[(size_t)lst[e] * 10 + l];
        s.x += a.x; s.y += a.y; s.z += a.z; s.w += a.w;
    }
    sconst[(size_t)u * 10 + l] = s;
    uint2 pk; pk.x = f2bf2(s.x, s.y); pk.y = f2bf2(s.z, s.w);
    y1b[(size_t)u * 10 + l] = pk;
}

__global__ __launch_bounds__(320) void lpa_mid(
    const uint2* __restrict__ ycur, const int* __restrict__ n_un,
    const int* __restrict__ ulist, const int* __restrict__ adj_s,
    const int* __restrict__ cnt_u, const float4* __restrict__ sconst,
    uint2* __restrict__ ynext) {
    int g = blockIdx.x * 32 + threadIdx.x / 10;
    int l = threadIdx.x % 10;
    if (g >= *n_un) return;
    int u = ulist[g];
    int cu = cnt_u[u];
    int cnt = cu < CAPS ? cu : CAPS;
    const int* lst = adj_s + (size_t)u * CAPS;
    float4 s = sconst[(size_t)u * 10 + l];
    int e = 0;
    for (; e + 8 <= cnt; e += 8) {
        uint2 v[8];
#pragma unroll
        for (int q = 0; q < 8; q++) v[q] = ycur[(size_t)lst[e + q] * 10 + l];
#pragma unroll
        for (int q = 0; q < 8; q++) {
            s.x += bf_lo(v[q].x); s.y += bf_hi(v[q].x);
            s.z += bf_lo(v[q].y); s.w += bf_hi(v[q].y);
        }
    }
    for (; e + 4 <= cnt; e += 4) {
        uint2 v[4];
#pragma unroll
        for (int q = 0; q < 4; q++) v[q] = ycur[(size_t)lst[e + q] * 10 + l];
#pragma unroll
        for (int q = 0; q < 4; q++) {
            s.x += bf_lo(v[q].x); s.y += bf_hi(v[q].x);
            s.z += bf_lo(v[q].y); s.w += bf_hi(v[q].y);
        }
    }
    for (; e < cnt; e++) {
        uint2 v = ycur[(size_t)lst[e] * 10 + l];
        s.x += bf_lo(v.x); s.y += bf_hi(v.x);
        s.z += bf_lo(v.y); s.w += bf_hi(v.y);
    }
    uint2 pk; pk.x = f2bf2(s.x, s.y); pk.y = f2bf2(s.z, s.w);
    ynext[(size_t)u * 10 + l] = pk;
}

__global__ __launch_bounds__(320) void lpa_last(
    const uint2* __restrict__ ycur, const int* __restrict__ n_un,
    const int* __restrict__ ulist, const int* __restrict__ adj_s,
    const int* __restrict__ cnt_u, const float4* __restrict__ sconst,
    float4* __restrict__ out_y) {
    int g = blockIdx.x * 32 + threadIdx.x / 10;
    int l = threadIdx.x % 10;
    if (g >= *n_un) return;
    int u = ulist[g];
    int cu = cnt_u[u];
    int cnt = cu < CAPS ? cu : CAPS;
    const int* lst = adj_s + (size_t)u * CAPS;
    float4 s = sconst[(size_t)u * 10 + l];
    int e = 0;
    for (; e + 8 <= cnt; e += 8) {
        uint2 v[8];
#pragma unroll
        for (int q = 0; q < 8; q++) v[q] = ycur[(size_t)lst[e + q] * 10 + l];
#pragma unroll
        for (int q = 0; q < 8; q++) {
            s.x += bf_lo(v[q].x); s.y += bf_hi(v[q].x);
            s.z += bf_lo(v[q].y); s.w += bf_hi(v[q].y);
        }
    }
    for (; e + 4 <= cnt; e += 4) {
        uint2 v[4];
#pragma unroll
        for (int q = 0; q < 4; q++) v[q] = ycur[(size_t)lst[e + q] * 10 + l];
#pragma unroll
        for (int q = 0; q < 4; q++) {
            s.x += bf_lo(v[q].x); s.y += bf_hi(v[q].x);
            s.z += bf_lo(v[q].y); s.w += bf_hi(v[q].y);
        }
    }
    for (; e < cnt; e++) {
        uint2 v = ycur[(size_t)lst[e] * 10 + l];
        s.x += bf_lo(v.x); s.y += bf_hi(v.x);
        s.z += bf_lo(v.y); s.w += bf_hi(v.y);
    }
    out_y[(size_t)u * 10 + l] = s;
}

// ---------------------------------------------------------------------------
extern "C" void kernel_launch(void* const* d_in, const int* in_sizes, int n_in,
                              void* d_out, int out_size, void* d_ws, size_t ws_size,
                              hipStream_t stream) {
    const float* feat   = (const float*)d_in[0];
    const float* labels = (const float*)d_in[1];
    const void*  mask   = d_in[2];
    const int*   src    = (const int*)d_in[3];
    const int*   dst    = (const int*)d_in[4];
    const float* W1     = (const float*)d_in[5];
    const float* b1     = (const float*)d_in[6];
    const float* W2     = (const float*)d_in[7];
    const float* b2     = (const float*)d_in[8];

    float* out_x = (float*)d_out;
    float* out_y = out_x + (size_t)Nn * NC;

    char* ws = (char*)d_ws;
    size_t off = 0;
    auto alloc = [&](size_t bytes) -> void* {
        void* p = ws + off;
        off += (bytes + 255) & ~(size_t)255;
        return p;
    };
    // --- zeroed header ---
    int* flag    = (int*)alloc(256);   // flag[0]=fmt, flag[1]=n_un
    int* n_un    = flag + 1;
    int* cnt_src = (int*)alloc((size_t)Nn * 4);
    int* cur_d   = (int*)alloc(512);
    int* cur_s   = (int*)alloc(512);
    size_t zero_bytes = off;
    // --- non-zeroed ---
    int* cnt_dst = (int*)alloc((size_t)Nn * 4);
    int* cnt_u   = (int*)alloc((size_t)Nn * 4);
    int* cnt_m   = (int*)alloc((size_t)Nn * 4);
    int* ulist   = (int*)alloc((size_t)Nn * 4);
    unsigned short* W1t = (unsigned short*)alloc((size_t)HID * INF_ * 2); // 64KB
    // --- big buffers; bucket bins alias h1b (dead before gemm1 writes) ---
    char* uni = (char*)alloc((size_t)Nn * HID * 2);        // 12.8MB union
    unsigned* bkt_d = (unsigned*)uni;                       // ~4.0MB
    unsigned* bkt_s = (unsigned*)(uni + (size_t)NB * CAPB_D * 4); // ~2.4MB
    unsigned short* h1b = (unsigned short*)uni;             // bf16 h1
    float* x1 = (float*)alloc((size_t)Nn * HID * 4);
    int* adj_s   = (int*)alloc((size_t)Nn * CAPS * 4);
    int* adj_dst = (int*)alloc((size_t)Nn * CAPD * 4);
    unsigned* h2b = (unsigned*)alloc((size_t)Nn * NC * 2);  // bf16 h2
    float* sconst = (float*)alloc((size_t)Nn * NC * 4);
    uint2* y1b = (uint2*)alloc((size_t)Nn * NC * 2);        // bf16 y ping
    uint2* y2b = (uint2*)alloc((size_t)Nn * NC * 2);        // bf16 y pong

    hipMemsetAsync(d_ws, 0, zero_bytes, stream);

    detect_fmt<<<49, 256, 0, stream>>>((const unsigned int*)mask, flag);
    prep_w1t<<<HID, INF_, 0, stream>>>(W1, W1t);
    bin_edges<<<NBLK, 256, 0, stream>>>(src, dst, mask, flag, cnt_src,
                                        cur_d, cur_s, bkt_d, bkt_s);
    build_csr_dst<<<NB, 256, 0, stream>>>(bkt_d, cur_d, adj_dst, cnt_dst);
    build_csr_src<<<NB, 256, 0, stream>>>(bkt_s, cur_s, mask, flag,
                                          adj_s, cnt_u, cnt_m);
    build_unmasked<<<196, 256, 0, stream>>>(mask, flag, n_un, ulist);

    gemm1<<<(Nn + G1_ROWS - 1) / G1_ROWS, 256, 0, stream>>>(feat, W1t, cnt_src, h1b);
    agg_relu1<<<Nn / 16, 256, 0, stream>>>((const uint4*)h1b, adj_dst, cnt_dst,
                                           (const float4*)b1, (float4*)x1);
    gemm2<<<196, 256, 0, stream>>>((const float4*)x1, (const float4*)W2,
                                   cnt_src, h2b);
    agg2<<<(Nn + 31) / 32, 320, 0, stream>>>((const uint2*)h2b, adj_dst, cnt_dst,
                                             (const float4*)b2, (float4*)out_x);

    lpa_init<<<(Nn * NC + 255) / 256, 256, 0, stream>>>(labels, mask, flag, out_y);
    lpa_const<<<(Nn + 31) / 32, 320, 0, stream>>>(
        (const float4*)labels, n_un, ulist, adj_s, cnt_m, (float4*)sconst, y1b);
    const uint2* cur = y1b;
    for (int i = 0; i < 8; i++) {          // iterations 2..9
        uint2* nxt = (i & 1) ? y1b : y2b;
        lpa_mid<<<(Nn + 31) / 32, 320, 0, stream>>>(
            cur, n_un, ulist, adj_s, cnt_u, (const float4*)sconst, nxt);
        cur = nxt;
    }
    lpa_last<<<(Nn + 31) / 32, 320, 0, stream>>>(   // iteration 10
        cur, n_un, ulist, adj_s, cnt_u, (const float4*)sconst, (float4*)out_y);
}

// Round 11
// 390.196 us; speedup vs baseline: 1.1928x; 1.0204x over previous
//
#include <hip/hip_runtime.h>

#define Nn 50000
#define Ee 800000
#define INF_ 256
#define HID 128
#define NC 40
#define CAPD 48      // adj_dst row capacity (Poisson(16) tail @48 ~1e-11)
#define CAPS 48      // adj_s row capacity (u-list front, m-list back)
#define LPA_ITERS 10
#define NB 98        // node buckets of 512
#define BSH 9
#define EPB 1024     // edges per bin_edges block
#define NBLK ((Ee + EPB - 1) / EPB)   // 782
#define CAPB_D 10240 // per-bucket bin capacity, dst direction (mean 8163)
#define CAPB_S 6144  // per-bucket bin capacity, src/unmasked (mean ~4081)

typedef __attribute__((ext_vector_type(8))) short bfrag;
typedef __attribute__((ext_vector_type(4))) float ffrag;

// ---- bf16 helpers (fp32 math, bf16 storage; RNE rounding) ------------------
__device__ inline unsigned f2bf2(float a, float b) {
    unsigned ua = __float_as_uint(a); ua += 0x7FFFu + ((ua >> 16) & 1u);
    unsigned ub = __float_as_uint(b); ub += 0x7FFFu + ((ub >> 16) & 1u);
    return (ua >> 16) | (ub & 0xFFFF0000u);
}
__device__ inline unsigned short f2bf(float a) {
    unsigned ua = __float_as_uint(a); ua += 0x7FFFu + ((ua >> 16) & 1u);
    return (unsigned short)(ua >> 16);
}
__device__ inline float bf_lo(unsigned u) { return __uint_as_float(u << 16); }
__device__ inline float bf_hi(unsigned u) { return __uint_as_float(u & 0xFFFF0000u); }

// ---------------------------------------------------------------------------
__global__ void detect_fmt(const unsigned int* __restrict__ m, int* flag) {
    int i = blockIdx.x * blockDim.x + threadIdx.x;
    if (i < 12500) {
        if (m[i] > 1u) atomicOr(flag, 1);
    }
}

__device__ inline bool read_mask(const void* mask, int node, int fmt) {
    if (fmt) return ((const unsigned char*)mask)[node] != 0;
    return ((const int*)mask)[node] != 0;
}

// ---------------------------------------------------------------------------
// Single-pass edge binning, both directions, one edge read. Fixed-capacity
// global bins; LDS staging -> coalesced writebacks. 782 blocks; parallel
// Hillis-Steele scans (no serial tid0 loops).
__global__ __launch_bounds__(256) void bin_edges(
    const int* __restrict__ src, const int* __restrict__ dst,
    const void* __restrict__ mask, const int* __restrict__ flag,
    int* __restrict__ cnt_src,
    int* __restrict__ cur_d, int* __restrict__ cur_s,
    unsigned* __restrict__ bkt_d, unsigned* __restrict__ bkt_s) {
    __shared__ unsigned stage_d[EPB];
    __shared__ unsigned stage_s[EPB];
    __shared__ int hd[NB], od[NB + 1], cd[NB], gd_[NB];
    __shared__ int hs[NB], os_[NB + 1], cs_[NB], gs_[NB];
    __shared__ int sc[256];
    int tid = threadIdx.x;
    int e0 = blockIdx.x * EPB;
    int fmt = *flag;
    if (tid < NB) { hd[tid] = 0; hs[tid] = 0; }
    __syncthreads();

    int rs[EPB / 256], rd[EPB / 256];
    unsigned um = 0;  // bit k: src unmasked
#pragma unroll
    for (int k = 0; k < EPB / 256; k++) {
        int e = e0 + tid + k * 256;
        rs[k] = -1; rd[k] = -1;
        if (e < Ee) {
            int s = src[e], d = dst[e];
            rs[k] = s; rd[k] = d;
            atomicAdd(&cnt_src[s], 1);
            atomicAdd(&hd[d >> BSH], 1);
            if (!read_mask(mask, s, fmt)) {
                um |= (1u << k);
                atomicAdd(&hs[s >> BSH], 1);
            }
        }
    }
    __syncthreads();
    // parallel scans: threads 0..127 scan hd, 128..255 scan hs (Hillis-Steele)
    {
        int seg = tid >> 7;      // 0 = dst, 1 = src
        int i = tid & 127;
        int v = 0;
        if (i < NB) v = seg ? hs[i] : hd[i];
        sc[tid] = v;
        __syncthreads();
#pragma unroll
        for (int offs = 1; offs < 128; offs <<= 1) {
            int add = (i >= offs) ? sc[tid - offs] : 0;
            __syncthreads();
            sc[tid] += add;
            __syncthreads();
        }
        if (i < NB) {
            int excl = i ? sc[tid - 1] : 0;
            if (seg == 0) od[i] = excl; else os_[i] = excl;
            if (i == NB - 1) {
                if (seg == 0) od[NB] = sc[tid]; else os_[NB] = sc[tid];
            }
        }
    }
    __syncthreads();
    if (tid < NB) {
        gd_[tid] = hd[tid] ? atomicAdd(&cur_d[tid], hd[tid]) : 0;
        gs_[tid] = hs[tid] ? atomicAdd(&cur_s[tid], hs[tid]) : 0;
        cd[tid] = od[tid];
        cs_[tid] = os_[tid];
    }
    __syncthreads();
#pragma unroll
    for (int k = 0; k < EPB / 256; k++) {
        if (rd[k] >= 0) {
            int p = atomicAdd(&cd[rd[k] >> BSH], 1);
            stage_d[p] = ((unsigned)rd[k] << 16) | (unsigned)rs[k];
            if (um & (1u << k)) {
                int q = atomicAdd(&cs_[rs[k] >> BSH], 1);
                stage_s[q] = ((unsigned)rs[k] << 16) | (unsigned)rd[k];
            }
        }
    }
    __syncthreads();
    int totd = od[NB];
    for (int i = tid; i < totd; i += 256) {
        int lo = 0, hi = NB;
        while (hi - lo > 1) {
            int mid = (lo + hi) >> 1;
            if (od[mid] <= i) lo = mid; else hi = mid;
        }
        int pos = gd_[lo] + (i - od[lo]);
        if (pos < CAPB_D) bkt_d[(size_t)lo * CAPB_D + pos] = stage_d[i];
    }
    int tots = os_[NB];
    for (int i = tid; i < tots; i += 256) {
        int lo = 0, hi = NB;
        while (hi - lo > 1) {
            int mid = (lo + hi) >> 1;
            if (os_[mid] <= i) lo = mid; else hi = mid;
        }
        int pos = gs_[lo] + (i - os_[lo]);
        if (pos < CAPB_S) bkt_s[(size_t)lo * CAPB_S + pos] = stage_s[i];
    }
}

// Phase B, both directions in one 196-block kernel (b<NB: dst; b>=NB: src).
__global__ __launch_bounds__(256) void build_csr_both(
    const unsigned* __restrict__ bkt_d, const int* __restrict__ cur_d,
    const unsigned* __restrict__ bkt_s, const int* __restrict__ cur_s,
    const void* __restrict__ mask, const int* __restrict__ flag,
    int* __restrict__ adj_dst, int* __restrict__ cnt_dst,
    int* __restrict__ adj_s, int* __restrict__ cnt_u, int* __restrict__ cnt_m) {
    __shared__ int lu[512], lm[512];
    int bb = blockIdx.x, tid = threadIdx.x;
    lu[tid] = 0; lu[tid + 256] = 0; lm[tid] = 0; lm[tid + 256] = 0;
    __syncthreads();
    if (bb < NB) {
        int b = bb;
        int n = cur_d[b]; if (n > CAPB_D) n = CAPB_D;
        int n0 = b << BSH;
        const unsigned* base = bkt_d + (size_t)b * CAPB_D;
        for (int i = tid; i < n; i += 256) {
            unsigned r = base[i];
            int d = r >> 16, s = r & 0xffff;
            int sl = atomicAdd(&lu[d - n0], 1);
            if (sl < CAPD) adj_dst[d * CAPD + sl] = s;
        }
        __syncthreads();
        int g0 = n0 + tid;
        if (g0 < Nn) cnt_dst[g0] = lu[tid];
        g0 += 256;
        if (g0 < Nn) cnt_dst[g0] = lu[tid + 256];
    } else {
        int b = bb - NB;
        int fmt = *flag;
        int n = cur_s[b]; if (n > CAPB_S) n = CAPB_S;
        int n0 = b << BSH;
        const unsigned* base = bkt_s + (size_t)b * CAPB_S;
        for (int i = tid; i < n; i += 256) {
            unsigned r = base[i];
            int s = r >> 16, d = r & 0xffff;
            if (read_mask(mask, d, fmt)) {
                int sl = atomicAdd(&lm[s - n0], 1);
                if (sl < CAPS) adj_s[s * CAPS + (CAPS - 1 - sl)] = d;
            } else {
                int sl = atomicAdd(&lu[s - n0], 1);
                if (sl < CAPS) adj_s[s * CAPS + sl] = d;
            }
        }
        __syncthreads();
        int g0 = n0 + tid;
        if (g0 < Nn) { cnt_u[g0] = lu[tid]; cnt_m[g0] = lm[tid]; }
        g0 += 256;
        if (g0 < Nn) { cnt_u[g0] = lu[tid + 256]; cnt_m[g0] = lm[tid + 256]; }
    }
}

__global__ void build_unmasked(const void* __restrict__ mask,
                               const int* __restrict__ flag,
                               int* n_un, int* __restrict__ ulist) {
    int i = blockIdx.x * blockDim.x + threadIdx.x;
    if (i < Nn) {
        if (!read_mask(mask, i, *flag)) {
            int p = atomicAdd(n_un, 1);
            ulist[p] = i;
        }
    }
}

// ---------------------------------------------------------------------------
// prep_w1t: W1 (fp32 [k][col]) -> W1t (bf16 [col][k]) once; 64KB output.
__global__ void prep_w1t(const float* __restrict__ W1,
                         unsigned short* __restrict__ W1t) {
    int c = blockIdx.x;      // 0..127
    int k = threadIdx.x;     // 0..255
    W1t[c * INF_ + k] = f2bf(W1[(size_t)k * HID + c]);
}

// ---------------------------------------------------------------------------
// GEMM1 (MFMA): h1 = (feat @ W1) * norm_src, bf16 in/out via matrix cores.
#define G1_ROWS 64
__global__ __launch_bounds__(256) void gemm1(
    const float* __restrict__ feat, const unsigned short* __restrict__ W1t,
    const int* __restrict__ cnt_src, unsigned short* __restrict__ h1b) {
    __shared__ unsigned short lA[G1_ROWS * 32];   // [row][k] bf16, 4KB
    __shared__ unsigned short lB[HID * 32];       // [col][k] bf16, 8KB
    const int tid = threadIdx.x;
    const int row0 = blockIdx.x * G1_ROWS;
    const int w = tid >> 6;
    const int l = tid & 63;
    const int lane15 = l & 15;
    const int quad = l >> 4;
    const int rw0 = w * 16;

    ffrag acc[8];
#pragma unroll
    for (int t = 0; t < 8; t++) acc[t] = (ffrag){0.f, 0.f, 0.f, 0.f};

    for (int k0 = 0; k0 < INF_; k0 += 32) {
#pragma unroll
        for (int p = 0; p < 2; p++) {
            int idx = tid + p * 256;
            int r = idx >> 3, c4 = idx & 7;
            int grow = row0 + r;
            float4 v = make_float4(0.f, 0.f, 0.f, 0.f);
            if (grow < Nn)
                v = *(const float4*)(feat + (size_t)grow * INF_ + k0 + c4 * 4);
            uint2 pk;
            pk.x = f2bf2(v.x, v.y);
            pk.y = f2bf2(v.z, v.w);
            *(uint2*)((char*)lA + r * 64 + c4 * 8) = pk;
        }
#pragma unroll
        for (int p = 0; p < 2; p++) {
            int idx = tid + p * 256;
            int col = idx >> 2, q = idx & 3;
            uint4 v = *(const uint4*)((const char*)W1t + col * 512 + k0 * 2 + q * 16);
            *(uint4*)((char*)lB + col * 64 + q * 16) = v;
        }
        __syncthreads();
        int arow = rw0 + lane15;
        bfrag af = *(const bfrag*)((const char*)lA + arow * 64 + quad * 16);
#pragma unroll
        for (int t = 0; t < 8; t++) {
            int col = t * 16 + lane15;
            bfrag bf = *(const bfrag*)((const char*)lB + col * 64 + quad * 16);
            acc[t] = __builtin_amdgcn_mfma_f32_16x16x32_bf16(af, bf, acc[t], 0, 0, 0);
        }
        __syncthreads();
    }
    float nrm[4];
#pragma unroll
    for (int i = 0; i < 4; i++) {
        int grow = row0 + rw0 + quad * 4 + i;
        int dg = (grow < Nn) ? cnt_src[grow] : 1;
        nrm[i] = rsqrtf((float)(dg > 1 ? dg : 1));
    }
#pragma unroll
    for (int t = 0; t < 8; t++) {
#pragma unroll
        for (int i = 0; i < 4; i++) {
            int grow = row0 + rw0 + quad * 4 + i;
            if (grow < Nn)
                h1b[(size_t)grow * HID + t * 16 + lane15] = f2bf(acc[t][i] * nrm[i]);
        }
    }
}

// ---------------------------------------------------------------------------
// agg1: x1[i,:] = relu( norm_dst[i] * sum_{e: dst=i} h1[src_e,:] + b1 )
__global__ __launch_bounds__(256) void agg_relu1(
    const uint4* __restrict__ h1b, const int* __restrict__ adj_dst,
    const int* __restrict__ cnt_dst, const float4* __restrict__ b1,
    float4* __restrict__ x1) {
    int node = blockIdx.x * 16 + (threadIdx.x >> 4);
    int l = threadIdx.x & 15;
    int dg = cnt_dst[node];
    int cnt = dg < CAPD ? dg : CAPD;
    const int* lst = adj_dst + (size_t)node * CAPD;
    float s0 = 0.f, s1 = 0.f, s2 = 0.f, s3 = 0.f;
    float s4 = 0.f, s5 = 0.f, s6 = 0.f, s7 = 0.f;
    int e = 0;
    for (; e + 8 <= cnt; e += 8) {
        uint4 u[8];
#pragma unroll
        for (int q = 0; q < 8; q++) u[q] = h1b[(size_t)lst[e + q] * 16 + l];
#pragma unroll
        for (int q = 0; q < 8; q++) {
            s0 += bf_lo(u[q].x); s1 += bf_hi(u[q].x);
            s2 += bf_lo(u[q].y); s3 += bf_hi(u[q].y);
            s4 += bf_lo(u[q].z); s5 += bf_hi(u[q].z);
            s6 += bf_lo(u[q].w); s7 += bf_hi(u[q].w);
        }
    }
    for (; e < cnt; e++) {
        uint4 u = h1b[(size_t)lst[e] * 16 + l];
        s0 += bf_lo(u.x); s1 += bf_hi(u.x);
        s2 += bf_lo(u.y); s3 += bf_hi(u.y);
        s4 += bf_lo(u.z); s5 += bf_hi(u.z);
        s6 += bf_lo(u.w); s7 += bf_hi(u.w);
    }
    float nrm = rsqrtf((float)(dg > 1 ? dg : 1));
    float4 bb0 = b1[l * 2], bb1 = b1[l * 2 + 1];
    float4 v0, v1;
    v0.x = fmaxf(s0 * nrm + bb0.x, 0.f);
    v0.y = fmaxf(s1 * nrm + bb0.y, 0.f);
    v0.z = fmaxf(s2 * nrm + bb0.z, 0.f);
    v0.w = fmaxf(s3 * nrm + bb0.w, 0.f);
    v1.x = fmaxf(s4 * nrm + bb1.x, 0.f);
    v1.y = fmaxf(s5 * nrm + bb1.y, 0.f);
    v1.z = fmaxf(s6 * nrm + bb1.z, 0.f);
    v1.w = fmaxf(s7 * nrm + bb1.w, 0.f);
    x1[(size_t)node * 32 + l * 2] = v0;
    x1[(size_t)node * 32 + l * 2 + 1] = v1;
}

// ---------------------------------------------------------------------------
// GEMM2: W2 (20KB) fully in LDS; one thread = one row; bf16 output rows.
__global__ __launch_bounds__(256) void gemm2(
    const float4* __restrict__ x1, const float4* __restrict__ W2,
    const int* __restrict__ cnt_src, unsigned* __restrict__ h2b) {
    __shared__ float lw[HID * NC];   // 20KB
    int tid = threadIdx.x;
    for (int i = tid; i < HID * NC / 4; i += 256)
        ((float4*)lw)[i] = W2[i];
    __syncthreads();
    int r = blockIdx.x * 256 + tid;
    if (r >= Nn) return;
    const float4* xr = x1 + (size_t)r * 32;
    float4 acc[10];
#pragma unroll
    for (int j = 0; j < 10; j++) acc[j] = make_float4(0.f, 0.f, 0.f, 0.f);
    for (int k4 = 0; k4 < 32; k4++) {
        float4 xv = xr[k4];
#pragma unroll
        for (int s = 0; s < 4; s++) {
            float x = s == 0 ? xv.x : (s == 1 ? xv.y : (s == 2 ? xv.z : xv.w));
            const float4* wrow = (const float4*)(lw + (k4 * 4 + s) * NC);
#pragma unroll
            for (int j = 0; j < 10; j++) {
                float4 w = wrow[j];
                acc[j].x += x * w.x; acc[j].y += x * w.y;
                acc[j].z += x * w.z; acc[j].w += x * w.w;
            }
        }
    }
    int dg = cnt_src[r];
    float nrm = rsqrtf((float)(dg > 1 ? dg : 1));
    uint2* out = (uint2*)(h2b + (size_t)r * 20);
#pragma unroll
    for (int j = 0; j < 10; j++) {
        uint2 pk;
        pk.x = f2bf2(acc[j].x * nrm, acc[j].y * nrm);
        pk.y = f2bf2(acc[j].z * nrm, acc[j].w * nrm);
        out[j] = pk;
    }
}

// ---------------------------------------------------------------------------
// agg2: out_x[i,c] = norm_dst[i] * sum_{e: dst=i} h2[src_e,c] + b2[c]
__global__ __launch_bounds__(320) void agg2(
    const uint2* __restrict__ h2b, const int* __restrict__ adj_dst,
    const int* __restrict__ cnt_dst, const float4* __restrict__ b2,
    float4* __restrict__ out_x) {
    int node = blockIdx.x * 32 + threadIdx.x / 10;
    int l = threadIdx.x % 10;
    if (node >= Nn) return;
    int dg = cnt_dst[node];
    int cnt = dg < CAPD ? dg : CAPD;
    const int* lst = adj_dst + (size_t)node * CAPD;
    float s0 = 0.f, s1 = 0.f, s2 = 0.f, s3 = 0.f;
    int e = 0;
    for (; e + 8 <= cnt; e += 8) {
        uint2 u[8];
#pragma unroll
        for (int q = 0; q < 8; q++) u[q] = h2b[(size_t)lst[e + q] * 10 + l];
#pragma unroll
        for (int q = 0; q < 8; q++) {
            s0 += bf_lo(u[q].x); s1 += bf_hi(u[q].x);
            s2 += bf_lo(u[q].y); s3 += bf_hi(u[q].y);
        }
    }
    for (; e + 4 <= cnt; e += 4) {
        uint2 u[4];
#pragma unroll
        for (int q = 0; q < 4; q++) u[q] = h2b[(size_t)lst[e + q] * 10 + l];
#pragma unroll
        for (int q = 0; q < 4; q++) {
            s0 += bf_lo(u[q].x); s1 += bf_hi(u[q].x);
            s2 += bf_lo(u[q].y); s3 += bf_hi(u[q].y);
        }
    }
    for (; e < cnt; e++) {
        uint2 u = h2b[(size_t)lst[e] * 10 + l];
        s0 += bf_lo(u.x); s1 += bf_hi(u.x);
        s2 += bf_lo(u.y); s3 += bf_hi(u.y);
    }
    float nrm = rsqrtf((float)(dg > 1 ? dg : 1));
    float4 bb = b2[l];
    float4 v;
    v.x = s0 * nrm + bb.x;
    v.y = s1 * nrm + bb.y;
    v.z = s2 * nrm + bb.z;
    v.w = s3 * nrm + bb.w;
    out_x[(size_t)node * 10 + l] = v;
}

// ---------------------------------------------------------------------------
// LPA. y_t[u] = S_const[u] + sum_{unmasked nbr v} y_{t-1}[v]; y_1 == S_const.
__global__ void lpa_init(const float* __restrict__ labels, const void* mask,
                         const int* __restrict__ flag, float* __restrict__ out_y) {
    int g = blockIdx.x * blockDim.x + threadIdx.x;
    if (g >= Nn * NC) return;
    int node = g / NC;
    if (read_mask(mask, node, *flag)) out_y[g] = labels[g];
}

__global__ __launch_bounds__(320) void lpa_const(
    const float4* __restrict__ labels, const int* __restrict__ n_un,
    const int* __restrict__ ulist, const int* __restrict__ adj_s,
    const int* __restrict__ cnt_m, float4* __restrict__ sconst,
    uint2* __restrict__ y1b) {
    int g = blockIdx.x * 32 + threadIdx.x / 10;
    int l = threadIdx.x % 10;
    if (g >= *n_un) return;
    int u = ulist[g];
    int cm = cnt_m[u];
    int cnt = cm < CAPS ? cm : CAPS;
    const int* lst = adj_s + (size_t)u * CAPS + (CAPS - cnt);
    float4 s = make_float4(0.f, 0.f, 0.f, 0.f);
    int e = 0;
    for (; e + 8 <= cnt; e += 8) {
        float4 v[8];
#pragma unroll
        for (int q = 0; q < 8; q++) v[q] = labels[(size_t)lst[e + q] * 10 + l];
#pragma unroll
        for (int q = 0; q < 8; q++) {
            s.x += v[q].x; s.y += v[q].y; s.z += v[q].z; s.w += v[q].w;
        }
    }
    for (; e + 4 <= cnt; e += 4) {
        float4 v[4];
#pragma unroll
        for (int q = 0; q < 4; q++) v[q] = labels[(size_t)lst[e + q] * 10 + l];
#pragma unroll
        for (int q = 0; q < 4; q++) {
            s.x += v[q].x; s.y += v[q].y; s.z += v[q].z; s.w += v[q].w;
        }
    }
    for (; e < cnt; e++) {
        float4 a = labels[(size_t)lst[e] * 10 + l];
        s.x += a.x; s.y += a.y; s.z += a.z; s.w += a.w;
    }
    sconst[(size_t)u * 10 + l] = s;
    uint2 pk; pk.x = f2bf2(s.x, s.y); pk.y = f2bf2(s.z, s.w);
    y1b[(size_t)u * 10 + l] = pk;
}

__global__ __launch_bounds__(320) void lpa_mid(
    const uint2* __restrict__ ycur, const int* __restrict__ n_un,
    const int* __restrict__ ulist, const int* __restrict__ adj_s,
    const int* __restrict__ cnt_u, const float4* __restrict__ sconst,
    uint2* __restrict__ ynext) {
    int g = blockIdx.x * 32 + threadIdx.x / 10;
    int l = threadIdx.x % 10;
    if (g >= *n_un) return;
    int u = ulist[g];
    int cu = cnt_u[u];
    int cnt = cu < CAPS ? cu : CAPS;
    const int* lst = adj_s + (size_t)u * CAPS;
    float4 s = sconst[(size_t)u * 10 + l];
    int e = 0;
    for (; e + 8 <= cnt; e += 8) {
        uint2 v[8];
#pragma unroll
        for (int q = 0; q < 8; q++) v[q] = ycur[(size_t)lst[e + q] * 10 + l];
#pragma unroll
        for (int q = 0; q < 8; q++) {
            s.x += bf_lo(v[q].x); s.y += bf_hi(v[q].x);
            s.z += bf_lo(v[q].y); s.w += bf_hi(v[q].y);
        }
    }
    for (; e + 4 <= cnt; e += 4) {
        uint2 v[4];
#pragma unroll
        for (int q = 0; q < 4; q++) v[q] = ycur[(size_t)lst[e + q] * 10 + l];
#pragma unroll
        for (int q = 0; q < 4; q++) {
            s.x += bf_lo(v[q].x); s.y += bf_hi(v[q].x);
            s.z += bf_lo(v[q].y); s.w += bf_hi(v[q].y);
        }
    }
    for (; e < cnt; e++) {
        uint2 v = ycur[(size_t)lst[e] * 10 + l];
        s.x += bf_lo(v.x); s.y += bf_hi(v.x);
        s.z += bf_lo(v.y); s.w += bf_hi(v.y);
    }
    uint2 pk; pk.x = f2bf2(s.x, s.y); pk.y = f2bf2(s.z, s.w);
    ynext[(size_t)u * 10 + l] = pk;
}

__global__ __launch_bounds__(320) void lpa_last(
    const uint2* __restrict__ ycur, const int* __restrict__ n_un,
    const int* __restrict__ ulist, const int* __restrict__ adj_s,
    const int* __restrict__ cnt_u, const float4* __restrict__ sconst,
    float4* __restrict__ out_y) {
    int g = blockIdx.x * 32 + threadIdx.x / 10;
    int l = threadIdx.x % 10;
    if (g >= *n_un) return;
    int u = ulist[g];
    int cu = cnt_u[u];
    int cnt = cu < CAPS ? cu : CAPS;
    const int* lst = adj_s + (size_t)u * CAPS;
    float4 s = sconst[(size_t)u * 10 + l];
    int e = 0;
    for (; e + 8 <= cnt; e += 8) {
        uint2 v[8];
#pragma unroll
        for (int q = 0; q < 8; q++) v[q] = ycur[(size_t)lst[e + q] * 10 + l];
#pragma unroll
        for (int q = 0; q < 8; q++) {
            s.x += bf_lo(v[q].x); s.y += bf_hi(v[q].x);
            s.z += bf_lo(v[q].y); s.w += bf_hi(v[q].y);
        }
    }
    for (; e + 4 <= cnt; e += 4) {
        uint2 v[4];
#pragma unroll
        for (int q = 0; q < 4; q++) v[q] = ycur[(size_t)lst[e + q] * 10 + l];
#pragma unroll
        for (int q = 0; q < 4; q++) {
            s.x += bf_lo(v[q].x); s.y += bf_hi(v[q].x);
            s.z += bf_lo(v[q].y); s.w += bf_hi(v[q].y);
        }
    }
    for (; e < cnt; e++) {
        uint2 v = ycur[(size_t)lst[e] * 10 + l];
        s.x += bf_lo(v.x); s.y += bf_hi(v.x);
        s.z += bf_lo(v.y); s.w += bf_hi(v.y);
    }
    out_y[(size_t)u * 10 + l] = s;
}

// ---------------------------------------------------------------------------
extern "C" void kernel_launch(void* const* d_in, const int* in_sizes, int n_in,
                              void* d_out, int out_size, void* d_ws, size_t ws_size,
                              hipStream_t stream) {
    const float* feat   = (const float*)d_in[0];
    const float* labels = (const float*)d_in[1];
    const void*  mask   = d_in[2];
    const int*   src    = (const int*)d_in[3];
    const int*   dst    = (const int*)d_in[4];
    const float* W1     = (const float*)d_in[5];
    const float* b1     = (const float*)d_in[6];
    const float* W2     = (const float*)d_in[7];
    const float* b2     = (const float*)d_in[8];

    float* out_x = (float*)d_out;
    float* out_y = out_x + (size_t)Nn * NC;

    char* ws = (char*)d_ws;
    size_t off = 0;
    auto alloc = [&](size_t bytes) -> void* {
        void* p = ws + off;
        off += (bytes + 255) & ~(size_t)255;
        return p;
    };
    // --- zeroed header ---
    int* flag    = (int*)alloc(256);   // flag[0]=fmt, flag[1]=n_un
    int* n_un    = flag + 1;
    int* cnt_src = (int*)alloc((size_t)Nn * 4);
    int* cur_d   = (int*)alloc(512);
    int* cur_s   = (int*)alloc(512);
    size_t zero_bytes = off;
    // --- non-zeroed ---
    int* cnt_dst = (int*)alloc((size_t)Nn * 4);
    int* cnt_u   = (int*)alloc((size_t)Nn * 4);
    int* cnt_m   = (int*)alloc((size_t)Nn * 4);
    int* ulist   = (int*)alloc((size_t)Nn * 4);
    unsigned short* W1t = (unsigned short*)alloc((size_t)HID * INF_ * 2); // 64KB
    // --- big buffers; bucket bins alias h1b (dead before gemm1 writes) ---
    char* uni = (char*)alloc((size_t)Nn * HID * 2);        // 12.8MB union
    unsigned* bkt_d = (unsigned*)uni;                       // ~4.0MB
    unsigned* bkt_s = (unsigned*)(uni + (size_t)NB * CAPB_D * 4); // ~2.4MB
    unsigned short* h1b = (unsigned short*)uni;             // bf16 h1
    float* x1 = (float*)alloc((size_t)Nn * HID * 4);
    int* adj_s   = (int*)alloc((size_t)Nn * CAPS * 4);
    int* adj_dst = (int*)alloc((size_t)Nn * CAPD * 4);
    unsigned* h2b = (unsigned*)alloc((size_t)Nn * NC * 2);  // bf16 h2
    float* sconst = (float*)alloc((size_t)Nn * NC * 4);
    uint2* y1b = (uint2*)alloc((size_t)Nn * NC * 2);        // bf16 y ping
    uint2* y2b = (uint2*)alloc((size_t)Nn * NC * 2);        // bf16 y pong

    hipMemsetAsync(d_ws, 0, zero_bytes, stream);

    detect_fmt<<<49, 256, 0, stream>>>((const unsigned int*)mask, flag);
    prep_w1t<<<HID, INF_, 0, stream>>>(W1, W1t);
    bin_edges<<<NBLK, 256, 0, stream>>>(src, dst, mask, flag, cnt_src,
                                        cur_d, cur_s, bkt_d, bkt_s);
    build_csr_both<<<NB * 2, 256, 0, stream>>>(bkt_d, cur_d, bkt_s, cur_s,
                                               mask, flag, adj_dst, cnt_dst,
                                               adj_s, cnt_u, cnt_m);
    build_unmasked<<<196, 256, 0, stream>>>(mask, flag, n_un, ulist);

    gemm1<<<(Nn + G1_ROWS - 1) / G1_ROWS, 256, 0, stream>>>(feat, W1t, cnt_src, h1b);
    agg_relu1<<<Nn / 16, 256, 0, stream>>>((const uint4*)h1b, adj_dst, cnt_dst,
                                           (const float4*)b1, (float4*)x1);
    gemm2<<<196, 256, 0, stream>>>((const float4*)x1, (const float4*)W2,
                                   cnt_src, h2b);
    agg2<<<(Nn + 31) / 32, 320, 0, stream>>>((const uint2*)h2b, adj_dst, cnt_dst,
                                             (const float4*)b2, (float4*)out_x);

    lpa_init<<<(Nn * NC + 255) / 256, 256, 0, stream>>>(labels, mask, flag, out_y);
    lpa_const<<<(Nn + 31) / 32, 320, 0, stream>>>(
        (const float4*)labels, n_un, ulist, adj_s, cnt_m, (float4*)sconst, y1b);
    const uint2* cur = y1b;
    for (int i = 0; i < 8; i++) {          // iterations 2..9
        uint2* nxt = (i & 1) ? y1b : y2b;
        lpa_mid<<<(Nn + 31) / 32, 320, 0, stream>>>(
            cur, n_un, ulist, adj_s, cnt_u, (const float4*)sconst, nxt);
        cur = nxt;
    }
    lpa_last<<<(Nn + 31) / 32, 320, 0, stream>>>(   // iteration 10
        cur, n_un, ulist, adj_s, cnt_u, (const float4*)sconst, (float4*)out_y);
}